// Round 5
// baseline (394.100 us; speedup 1.0000x reference)
//
#include <hip/hip_runtime.h>
#include <hip/hip_bf16.h>

#define NDIM 256
#define FDIM 32
#define HOPS 4
#define NPB 8   // nodes per init block

typedef __attribute__((ext_vector_type(8))) short short8;
typedef __attribute__((ext_vector_type(4))) float f32x4;
typedef __attribute__((ext_vector_type(2))) float f32x2;

// ---------- helpers ----------
__device__ inline float b2f(unsigned short u) {
    union { unsigned int i; float f; } v; v.i = ((unsigned int)u) << 16; return v.f;
}
__device__ inline unsigned short f2b(float f) {
    union { float f; unsigned int i; } v; v.f = f;
    unsigned int r = v.i + 0x7FFF + ((v.i >> 16) & 1);
    return (unsigned short)(r >> 16);
}
__device__ inline unsigned char f2fp8(float v) {
    return (unsigned char)(__builtin_amdgcn_cvt_pk_fp8_f32(v, v, 0, false) & 0xFF);
}

// ---------- prep mega ----------
// blocks [0, histB): hist
// blocks [histB, histB+773): weight prep
//   bb <256         : wtrans WtB[hop][nn][k] = bf16(W_upd[hop][k][nn])
//   bb 256..259     : cvec[hop] = b_msg[hop] @ Wu2[hop]
//   bb 260          : zero geInt + h8 pad row
//   bb 261..516     : Am = bf16(W_msg) flat copy (8 matrices, coalesced)
//   bb 517..772     : BmT[hop][nn][j] = bf16(Wu2[hop][j][nn]) 32x32 tile transpose
// rest: init_h, NPB nodes per block
__global__ __launch_bounds__(256) void prep_mega_kernel(
        const int* __restrict__ dst, int* __restrict__ deg, int E, int histB,
        const float* __restrict__ Wm, const float* __restrict__ Wu,
        const float* __restrict__ bm,
        unsigned short* __restrict__ WtB,
        unsigned short* __restrict__ Am, unsigned short* __restrict__ BmT,
        float* __restrict__ cvec, int* __restrict__ geInt,
        unsigned char* __restrict__ h8row,
        const float* __restrict__ nodes, const int* __restrict__ node_types,
        const float* __restrict__ type_emb, const float* __restrict__ W_proj,
        const float* __restrict__ b_proj,
        unsigned short* __restrict__ h, unsigned char* __restrict__ h8, int n) {
    __shared__ float T[32][33];
    __shared__ float sb[256];
    int b = blockIdx.x;
    int t = threadIdx.x;

    if (b < histB) {
        // ---- hist ----
        int e = b * 256 + t;
        if (e < E) atomicAdd(&deg[dst[e]], 1);
    } else if (b < histB + 773) {
        int bb = b - histB;
        if (bb < 256) {
            // ---- wtrans: WtB[hop][nn][k] = W_upd[hop][k][nn] ----
            int hop = bb >> 6;
            int rem = bb & 63;
            int k0 = (rem & 7) * 32, n0 = (rem >> 3) * 32;
            const float* src = Wu + (size_t)hop * 512 * 256;
            unsigned short* dstp = WtB + (size_t)hop * 256 * 256;
            int tr = t >> 5, tc = t & 31;
#pragma unroll
            for (int r = 0; r < 4; ++r) {
                int k = tr + r * 8;
                T[tc][k] = src[(size_t)(k0 + k) * 256 + n0 + tc];
            }
            __syncthreads();
#pragma unroll
            for (int r = 0; r < 4; ++r) {
                int nn = tr + r * 8;
                dstp[(size_t)(n0 + nn) * 256 + k0 + tc] = f2b(T[nn][tc]);
            }
        } else if (bb < 260) {
            // ---- cvec[hop] = b_msg[hop] @ Wu2[hop] ----
            int hop = bb - 256;
            sb[t] = bm[hop * 256 + t];
            __syncthreads();
            const float* B = Wu + (size_t)hop * 512 * 256 + (size_t)256 * 256;
            float acc = 0.f;
#pragma unroll 8
            for (int j = 0; j < 256; ++j) acc += sb[j] * B[(size_t)j * 256 + t];
            cvec[hop * 256 + t] = acc;
        } else if (bb == 260) {
            geInt[t] = 0;
            h8row[t] = 0;
        } else if (bb < 517) {
            // ---- Am: flat fp32->bf16 of W_msg (matrix m occupies [m*65536, +65536)) ----
            size_t base = (size_t)(bb - 261) * 2048 + (size_t)t * 8;
            float4 a0 = *(const float4*)(Wm + base);
            float4 a1 = *(const float4*)(Wm + base + 4);
            ushort4 o0, o1;
            o0.x = f2b(a0.x); o0.y = f2b(a0.y); o0.z = f2b(a0.z); o0.w = f2b(a0.w);
            o1.x = f2b(a1.x); o1.y = f2b(a1.y); o1.z = f2b(a1.z); o1.w = f2b(a1.w);
            *(ushort4*)(Am + base) = o0;
            *(ushort4*)(Am + base + 4) = o1;
        } else {
            // ---- BmT: BmT[hop][nn][j] = bf16(Wu2[hop][j][nn]) ----
            int tb = bb - 517;
            int hop = tb >> 6;
            int rem = tb & 63;
            int j0 = (rem & 7) * 32, n0 = (rem >> 3) * 32;
            const float* srcp = Wu + (size_t)hop * 512 * 256 + (size_t)256 * 256;
            unsigned short* dstp = BmT + (size_t)hop * 256 * 256;
            int tr = t >> 5, tc = t & 31;
#pragma unroll
            for (int r = 0; r < 4; ++r) {
                int j = tr + r * 8;
                T[tc][j] = srcp[(size_t)(j0 + j) * 256 + n0 + tc];
            }
            __syncthreads();
#pragma unroll
            for (int r = 0; r < 4; ++r) {
                int nn = tr + r * 8;
                dstp[(size_t)(n0 + nn) * 256 + j0 + tc] = f2b(T[nn][tc]);
            }
        }
    } else {
        // ---- init_h, NPB nodes per block ----
        int v0 = (b - histB - 773) * NPB;
        {
            int j = t >> 5, f = t & 31;      // 256 threads = 8 x 32
            int v = v0 + j;
            sb[t] = (v < n) ? nodes[(size_t)v * FDIM + f] : 0.f;
        }
        __syncthreads();
        float acc[NPB];
#pragma unroll
        for (int j = 0; j < NPB; ++j) {
            int v = v0 + j;
            acc[j] = (v < n) ? (b_proj[t] + type_emb[(size_t)node_types[v] * NDIM + t]) : 0.f;
        }
#pragma unroll 4
        for (int k = 0; k < FDIM; ++k) {
            float wv = W_proj[(size_t)k * NDIM + t];
#pragma unroll
            for (int j = 0; j < NPB; ++j)
                acc[j] += sb[j * FDIM + k] * wv;
        }
#pragma unroll
        for (int j = 0; j < NPB; ++j) {
            int v = v0 + j;
            if (v < n) {
                h[(size_t)v * NDIM + t] = f2b(acc[j]);
                h8[(size_t)v * NDIM + t] = f2fp8(acc[j]);
            }
        }
    }
}

// ---------- scan phase 1 (blocks 0..nch-1) + mm via MFMA (blocks nch..nch+7) ----------
__global__ __launch_bounds__(1024) void scan1_mm_kernel(
        const int* __restrict__ deg, int* __restrict__ rowptr,
        int* __restrict__ bsum, int nch, int n,
        const unsigned short* __restrict__ Am, const unsigned short* __restrict__ BmT,
        unsigned short* __restrict__ WtA, unsigned short* __restrict__ WtC) {
    int t = threadIdx.x;
    int b = blockIdx.x;
    if (b < nch) {
        __shared__ int wsum[16];
        int i = b * 1024 + t;
        int v = 0;
        if (i < n) v = (deg[i] + 7) & ~7;
        int lane = t & 63, wid = t >> 6;
        int x = v;
#pragma unroll
        for (int d = 1; d < 64; d <<= 1) {
            int u = __shfl_up(x, d, 64);
            if (lane >= d) x += u;
        }
        if (lane == 63) wsum[wid] = x;
        __syncthreads();
        if (wid == 0) {
            int ws = (lane < 16) ? wsum[lane] : 0;
#pragma unroll
            for (int d = 1; d < 16; d <<= 1) {
                int u = __shfl_up(ws, d, 64);
                if (lane >= d) ws += u;
            }
            if (lane < 16) wsum[lane] = ws;
        }
        __syncthreads();
        int excl = (wid > 0 ? wsum[wid - 1] : 0) + x - v;
        if (i < n) rowptr[i] = excl;
        if (t == 1023) bsum[b] = wsum[15];
        return;
    }

    // ---- MFMA mm, all-bf16 operands ----
    int m = b - nch;                        // 0..7
    int hop = m >> 1, which = m & 1;
    const unsigned short* A = Am + (size_t)m * 65536;          // [k][j] bf16
    const unsigned short* B = BmT + (size_t)hop * 65536;       // [n][j] bf16
    unsigned short* W = (which ? WtC : WtA) + (size_t)hop * 65536;  // [n][k]
    int wave = t >> 6, lane = t & 63;
    int l16 = lane & 15, quad = lane >> 4;
    int k0 = (wave & 3) * 64;
    int n0 = (wave >> 2) * 64;
    f32x4 acc[4][4];
#pragma unroll
    for (int i = 0; i < 4; ++i)
#pragma unroll
        for (int j = 0; j < 4; ++j) acc[i][j] = (f32x4)(0.f);

    for (int j0 = 0; j0 < 256; j0 += 32) {
        short8 af[4], bfr[4];
#pragma unroll
        for (int kt = 0; kt < 4; ++kt)
            af[kt] = *(const short8*)(A + (size_t)(k0 + kt * 16 + l16) * 256 + j0 + quad * 8);
#pragma unroll
        for (int nt = 0; nt < 4; ++nt)
            bfr[nt] = *(const short8*)(B + (size_t)(n0 + nt * 16 + l16) * 256 + j0 + quad * 8);
#pragma unroll
        for (int kt = 0; kt < 4; ++kt)
#pragma unroll
            for (int nt = 0; nt < 4; ++nt)
                acc[kt][nt] = __builtin_amdgcn_mfma_f32_16x16x32_bf16(af[kt], bfr[nt], acc[kt][nt], 0, 0, 0);
    }
    // D layout: col = l16 (n), row = quad*4 + r (k). Store transposed W[n][k].
#pragma unroll
    for (int kt = 0; kt < 4; ++kt)
#pragma unroll
        for (int nt = 0; nt < 4; ++nt) {
            int k = k0 + kt * 16 + quad * 4;
            int nn = n0 + nt * 16 + l16;
            ushort4 o;
            o.x = f2b(acc[kt][nt][0]); o.y = f2b(acc[kt][nt][1]);
            o.z = f2b(acc[kt][nt][2]); o.w = f2b(acc[kt][nt][3]);
            *(ushort4*)&W[(size_t)nn * 256 + k] = o;
        }
}

// ---------- scan phase 2: add block offsets, write cursor, rowptr[n] ----------
__global__ __launch_bounds__(1024) void scan2_kernel(
        int* __restrict__ rowptr, int* __restrict__ cursor,
        const int* __restrict__ bsum, int nch, int n) {
    __shared__ int soff, stot;
    int t = threadIdx.x;
    int b = blockIdx.x;
    if (t < 64) {
        int s = (t < nch) ? bsum[t] : 0;
        int x = s;
#pragma unroll
        for (int d = 1; d < 64; d <<= 1) {
            int u = __shfl_up(x, d, 64);
            if (t >= d) x += u;
        }
        if (t == 63) stot = x;
        if (t == b) soff = x - s;   // exclusive prefix for this block
    }
    __syncthreads();
    int i = b * 1024 + t;
    if (i < n) {
        int r = rowptr[i] + soff;
        rowptr[i] = r;
        cursor[i] = r;
    }
    if (b == 0 && t == 0) rowptr[n] = stot;
}

// ---------- fill (blocks 0..fillB-1) + pad (rest); disjoint col ranges ----------
__global__ void fillpad_kernel(const int* __restrict__ src, const int* __restrict__ dst,
                               int* __restrict__ cursor,
                               const int* __restrict__ rowptr, const int* __restrict__ deg,
                               int* __restrict__ col, int E, int fillB, int n) {
    int b = blockIdx.x;
    int t = threadIdx.x;
    if (b < fillB) {
        int e = b * 256 + t;
        if (e < E) {
            int d = dst[e];
            int p = atomicAdd(&cursor[d], 1);
            col[p] = src[e];
        }
    } else {
        int v = (b - fillB) * 256 + t;
        if (v < n) {
            int s = rowptr[v] + deg[v];
            int e0 = rowptr[v + 1];
            for (int i = s; i < e0; ++i) col[i] = n;
        }
    }
}

// ---------- neighbor sum: TWO column-half passes so the gather working set (3.2MB)
// fits each XCD's 4MiB L2 (h8 full = 6.4MB thrashes -> L3 random BW was the pole).
// Pass c0 in {0,128}: 32 lanes x 4B = 128B per neighbor row half; same 8-outstanding
// gathers per chunk (MLP preserved, R3 lesson); summation order per output element
// identical to the single-pass version -> bit-identical results.
// S stores are nontemporal so 6.4MB of S writes don't evict the resident h8 half.
__global__ __launch_bounds__(256) void agg_kernel(const unsigned char* __restrict__ h8,
                                                  const int* __restrict__ rowptr,
                                                  const int* __restrict__ col,
                                                  unsigned short* __restrict__ S, int n,
                                                  int c0) {
    int wave = threadIdx.x >> 6;
    int lane = threadIdx.x & 63;
    int half = lane >> 5;
    int hl = lane & 31;
    int v = blockIdx.x * 8 + wave * 2 + half;
    if (v >= n) return;
    int beg = rowptr[v], end = rowptr[v + 1];
    float a[4];
#pragma unroll
    for (int e = 0; e < 4; ++e) a[e] = 0.f;
    int cofs = c0 + hl * 4;
    for (int i = beg; i < end; i += 8) {
        int cc[8];
#pragma unroll
        for (int j = 0; j < 8; ++j) cc[j] = col[i + j];
        unsigned int x[8];
#pragma unroll
        for (int j = 0; j < 8; ++j)
            x[j] = *(const unsigned int*)(h8 + (size_t)cc[j] * NDIM + cofs);
#pragma unroll
        for (int j = 0; j < 8; ++j) {
            f32x2 p0 = __builtin_amdgcn_cvt_pk_f32_fp8(x[j], false);
            f32x2 p1 = __builtin_amdgcn_cvt_pk_f32_fp8(x[j], true);
            a[0] += p0[0]; a[1] += p0[1]; a[2] += p1[0]; a[3] += p1[1];
        }
    }
    unsigned long long o;
    unsigned short* op = (unsigned short*)&o;
#pragma unroll
    for (int e = 0; e < 4; ++e) op[e] = f2b(a[e]);
    __builtin_nontemporal_store(o, (unsigned long long*)(S + (size_t)v * NDIM + cofs));
}

// ---------- fused hop GEMM: BM=128 BN=64 BK=64 two-phase dual-acc (R20 config) ----------
#define BM 128
#define BN 64
#define BK 64
#define ASTR (BK + 8)

template <bool LAST>
__global__ __launch_bounds__(256) void gemm_hop_kernel(const unsigned short* __restrict__ S,
                                                       const unsigned short* __restrict__ hcur,
                                                       const int* __restrict__ deg,
                                                       const unsigned short* __restrict__ WtA,
                                                       const unsigned short* __restrict__ WtB,
                                                       const unsigned short* __restrict__ WtC,
                                                       const float* __restrict__ bupd,
                                                       const float* __restrict__ cvec,
                                                       unsigned short* __restrict__ Out,
                                                       unsigned char* __restrict__ Out8,
                                                       int* __restrict__ geInt, int n) {
    __shared__ unsigned short As[BM][ASTR];
    __shared__ unsigned short Bs[BN][ASTR];
    __shared__ unsigned short Cs[BN][ASTR];
    __shared__ int smax[BN];
    int t = threadIdx.x;
    int lane = t & 63;
    int w = t >> 6;
    int wm = w >> 1, wn = w & 1;
    int quad = lane >> 4, l16 = lane & 15;
    int row0 = blockIdx.x * BM;
    int n0 = blockIdx.y * BN;

    if (LAST) {
        if (t < BN) smax[t] = 0;
    }

    f32x4 acc1[4][2], acc2[4][2];
#pragma unroll
    for (int i = 0; i < 4; ++i)
#pragma unroll
        for (int j = 0; j < 2; ++j) { acc1[i][j] = (f32x4)(0.f); acc2[i][j] = (f32x4)(0.f); }

    // phase 1: acc1 += S @ M1^T
    for (int k0 = 0; k0 < NDIM; k0 += BK) {
        __syncthreads();
#pragma unroll
        for (int h2 = 0; h2 < 4; ++h2) {
            int c = t + h2 * 256;
            int r = c >> 3;
            int ko = (c & 7) * 8;
            int grow = row0 + r; if (grow >= n) grow = n - 1;
            *(uint4*)&As[r][ko] = *(const uint4*)(S + (size_t)grow * NDIM + k0 + ko);
        }
#pragma unroll
        for (int h2 = 0; h2 < 2; ++h2) {
            int c = t + h2 * 256;
            int r = c >> 3;
            int ko = (c & 7) * 8;
            *(uint4*)&Bs[r][ko] = *(const uint4*)(WtA + (size_t)(n0 + r) * NDIM + k0 + ko);
        }
        __syncthreads();
#pragma unroll
        for (int ks = 0; ks < BK; ks += 32) {
            short8 af[4], bf[2];
#pragma unroll
            for (int mt = 0; mt < 4; ++mt)
                af[mt] = *(const short8*)&As[wm * 64 + mt * 16 + l16][ks + quad * 8];
#pragma unroll
            for (int nt = 0; nt < 2; ++nt)
                bf[nt] = *(const short8*)&Bs[wn * 32 + nt * 16 + l16][ks + quad * 8];
#pragma unroll
            for (int mt = 0; mt < 4; ++mt)
#pragma unroll
                for (int nt = 0; nt < 2; ++nt)
                    acc1[mt][nt] = __builtin_amdgcn_mfma_f32_16x16x32_bf16(af[mt], bf[nt], acc1[mt][nt], 0, 0, 0);
        }
    }
    // phase 2: acc1 += h @ Wu1^T ; acc2 += h @ M2^T
    for (int k0 = 0; k0 < NDIM; k0 += BK) {
        __syncthreads();
#pragma unroll
        for (int h2 = 0; h2 < 4; ++h2) {
            int c = t + h2 * 256;
            int r = c >> 3;
            int ko = (c & 7) * 8;
            int grow = row0 + r; if (grow >= n) grow = n - 1;
            *(uint4*)&As[r][ko] = *(const uint4*)(hcur + (size_t)grow * NDIM + k0 + ko);
        }
#pragma unroll
        for (int h2 = 0; h2 < 2; ++h2) {
            int c = t + h2 * 256;
            int r = c >> 3;
            int ko = (c & 7) * 8;
            size_t widx = (size_t)(n0 + r) * NDIM + k0 + ko;
            *(uint4*)&Bs[r][ko] = *(const uint4*)(WtB + widx);
            *(uint4*)&Cs[r][ko] = *(const uint4*)(WtC + widx);
        }
        __syncthreads();
#pragma unroll
        for (int ks = 0; ks < BK; ks += 32) {
            short8 af[4], bf[2], cf[2];
#pragma unroll
            for (int mt = 0; mt < 4; ++mt)
                af[mt] = *(const short8*)&As[wm * 64 + mt * 16 + l16][ks + quad * 8];
#pragma unroll
            for (int nt = 0; nt < 2; ++nt) {
                bf[nt] = *(const short8*)&Bs[wn * 32 + nt * 16 + l16][ks + quad * 8];
                cf[nt] = *(const short8*)&Cs[wn * 32 + nt * 16 + l16][ks + quad * 8];
            }
#pragma unroll
            for (int mt = 0; mt < 4; ++mt)
#pragma unroll
                for (int nt = 0; nt < 2; ++nt) {
                    acc1[mt][nt] = __builtin_amdgcn_mfma_f32_16x16x32_bf16(af[mt], bf[nt], acc1[mt][nt], 0, 0, 0);
                    acc2[mt][nt] = __builtin_amdgcn_mfma_f32_16x16x32_bf16(af[mt], cf[nt], acc2[mt][nt], 0, 0, 0);
                }
        }
    }
    // epilogue
#pragma unroll
    for (int mt = 0; mt < 4; ++mt) {
#pragma unroll
        for (int nt = 0; nt < 2; ++nt) {
            int lcol = wn * 32 + nt * 16 + l16;
            int col = n0 + lcol;
            float bu = bupd[col];
            float cv = cvec[col];
            float cmax = 0.f;
#pragma unroll
            for (int r = 0; r < 4; ++r) {
                int row = row0 + wm * 64 + mt * 16 + quad * 4 + r;
                if (row < n) {
                    float dg = (float)deg[row];
                    float v = fmaxf(acc1[mt][nt][r] + dg * (acc2[mt][nt][r] + cv) + bu, 0.f);
                    Out[(size_t)row * NDIM + col] = f2b(v);
                    if (!LAST) Out8[(size_t)row * NDIM + col] = f2fp8(v);
                    if (LAST) cmax = fmaxf(cmax, v);
                }
            }
            if (LAST) atomicMax(&smax[lcol], __float_as_int(cmax));
        }
    }
    if (LAST) {
        __syncthreads();
        if (t < BN) atomicMax(&geInt[n0 + t], smax[t]);
    }
}

// ---------- final ----------
__global__ __launch_bounds__(1024) void out_kernel(const float* __restrict__ ge,
                                                   const float* __restrict__ W_out,
                                                   const float* __restrict__ b_out,
                                                   float* __restrict__ out) {
    __shared__ float red[4][NDIM];
    int t = threadIdx.x & 255;
    int g = threadIdx.x >> 8;
    float acc = 0.f;
#pragma unroll 8
    for (int kk = 0; kk < 64; ++kk) {
        int k = g * 64 + kk;
        acc += ge[k] * W_out[k * NDIM + t];
    }
    red[g][t] = acc;
    __syncthreads();
    if (g == 0)
        out[t] = b_out[t] + red[0][t] + red[1][t] + red[2][t] + red[3][t];
}

// ---------- launch ----------
extern "C" void kernel_launch(void* const* d_in, const int* in_sizes, int n_in,
                              void* d_out, int out_size, void* d_ws, size_t ws_size,
                              hipStream_t stream) {
    const float* nodes      = (const float*)d_in[0];
    const int*   edges      = (const int*)d_in[1];
    const int*   node_types = (const int*)d_in[2];
    const float* type_emb   = (const float*)d_in[3];
    const float* W_proj     = (const float*)d_in[4];
    const float* b_proj     = (const float*)d_in[5];
    const float* W_msg      = (const float*)d_in[6];
    const float* b_msg      = (const float*)d_in[7];
    const float* W_upd      = (const float*)d_in[8];
    const float* b_upd      = (const float*)d_in[9];
    const float* W_out      = (const float*)d_in[10];
    const float* b_out      = (const float*)d_in[11];

    int n = in_sizes[2];
    int E = in_sizes[1] / 2;
    const int* src = edges;
    const int* dst = edges + E;

    size_t off = 0;
    auto alloc = [&](size_t bytes) {
        void* p = (char*)d_ws + off;
        off += (bytes + 255) & ~(size_t)255;
        return p;
    };
    int* deg    = (int*)alloc((size_t)(n + 4096) * 4);
    int* rowptr = (int*)alloc((size_t)(n + 1) * 4);
    int* cursor = (int*)alloc((size_t)n * 4);
    int* bsum   = (int*)alloc((size_t)256 * 4);
    int* col    = (int*)alloc((size_t)(E + 8 * n) * 4);
    unsigned short* WtA = (unsigned short*)alloc((size_t)HOPS * 256 * 256 * 2);
    unsigned short* WtB = (unsigned short*)alloc((size_t)HOPS * 256 * 256 * 2);
    unsigned short* WtC = (unsigned short*)alloc((size_t)HOPS * 256 * 256 * 2);
    unsigned short* Am  = (unsigned short*)alloc((size_t)8 * 256 * 256 * 2);
    unsigned short* BmT = (unsigned short*)alloc((size_t)HOPS * 256 * 256 * 2);
    float* cvec = (float*)alloc((size_t)HOPS * 256 * 4);
    int* geInt  = (int*)alloc((size_t)256 * 4);
    unsigned short* hA  = (unsigned short*)alloc((size_t)(n + 1) * NDIM * 2);
    unsigned short* hB  = (unsigned short*)alloc((size_t)(n + 1) * NDIM * 2);
    unsigned short* Sb  = (unsigned short*)alloc((size_t)n * NDIM * 2);
    unsigned char* h8   = (unsigned char*)alloc((size_t)(n + 1) * NDIM);

    hipMemsetAsync(deg, 0, (size_t)(n + 4096) * 4, stream);
    int eb = (E + 255) / 256;
    int pb = (n + 255) / 256;
    int ib = (n + NPB - 1) / NPB;
    int nch = (n + 1023) / 1024;   // <= 64 chunks (n <= 64K)
    prep_mega_kernel<<<eb + 773 + ib, 256, 0, stream>>>(
        dst, deg, E, eb,
        W_msg, W_upd, b_msg, WtB, Am, BmT, cvec, geInt, h8 + (size_t)n * NDIM,
        nodes, node_types, type_emb, W_proj, b_proj, hA, h8, n);
    scan1_mm_kernel<<<nch + 8, 1024, 0, stream>>>(deg, rowptr, bsum, nch, n, Am, BmT, WtA, WtC);
    scan2_kernel<<<nch, 1024, 0, stream>>>(rowptr, cursor, bsum, nch, n);
    fillpad_kernel<<<eb + pb, 256, 0, stream>>>(src, dst, cursor, rowptr, deg, col, E, eb, n);

    unsigned short* h  = hA;
    unsigned short* ho = hB;
    int gx = (n + BM - 1) / BM;
    dim3 ggrid(gx, NDIM / BN);
    for (int i = 0; i < HOPS; ++i) {
        agg_kernel<<<(n + 7) / 8, 256, 0, stream>>>(h8, rowptr, col, Sb, n, 0);
        agg_kernel<<<(n + 7) / 8, 256, 0, stream>>>(h8, rowptr, col, Sb, n, 128);
        size_t wofs = (size_t)i * 256 * 256;
        if (i == HOPS - 1)
            gemm_hop_kernel<true><<<ggrid, 256, 0, stream>>>(
                Sb, h, deg, WtA + wofs, WtB + wofs, WtC + wofs,
                b_upd + (size_t)i * NDIM, cvec + (size_t)i * NDIM, ho, h8, geInt, n);
        else
            gemm_hop_kernel<false><<<ggrid, 256, 0, stream>>>(
                Sb, h, deg, WtA + wofs, WtB + wofs, WtC + wofs,
                b_upd + (size_t)i * NDIM, cvec + (size_t)i * NDIM, ho, h8, geInt, n);
        unsigned short* tmp = h; h = ho; ho = tmp;
    }
    out_kernel<<<1, 1024, 0, stream>>>((const float*)geInt, W_out, b_out, (float*)d_out);
}

// Round 6
// 365.557 us; speedup vs baseline: 1.0781x; 1.0781x over previous
//
#include <hip/hip_runtime.h>
#include <hip/hip_bf16.h>

#define NDIM 256
#define FDIM 32
#define HOPS 4
#define NPB 8   // nodes per init block

typedef __attribute__((ext_vector_type(8))) short short8;
typedef __attribute__((ext_vector_type(4))) float f32x4;
typedef __attribute__((ext_vector_type(2))) float f32x2;

// ---------- helpers ----------
__device__ inline float b2f(unsigned short u) {
    union { unsigned int i; float f; } v; v.i = ((unsigned int)u) << 16; return v.f;
}
__device__ inline unsigned short f2b(float f) {
    union { float f; unsigned int i; } v; v.f = f;
    unsigned int r = v.i + 0x7FFF + ((v.i >> 16) & 1);
    return (unsigned short)(r >> 16);
}
__device__ inline unsigned char f2fp8(float v) {
    return (unsigned char)(__builtin_amdgcn_cvt_pk_fp8_f32(v, v, 0, false) & 0xFF);
}

// ---------- prep mega ----------
__global__ __launch_bounds__(256) void prep_mega_kernel(
        const int* __restrict__ dst, int* __restrict__ deg, int E, int histB,
        const float* __restrict__ Wm, const float* __restrict__ Wu,
        const float* __restrict__ bm,
        unsigned short* __restrict__ WtB,
        unsigned short* __restrict__ Am, unsigned short* __restrict__ BmT,
        float* __restrict__ cvec, int* __restrict__ geInt,
        unsigned char* __restrict__ h8row,
        const float* __restrict__ nodes, const int* __restrict__ node_types,
        const float* __restrict__ type_emb, const float* __restrict__ W_proj,
        const float* __restrict__ b_proj,
        unsigned short* __restrict__ h, unsigned char* __restrict__ h8, int n) {
    __shared__ float T[32][33];
    __shared__ float sb[256];
    int b = blockIdx.x;
    int t = threadIdx.x;

    if (b < histB) {
        int e = b * 256 + t;
        if (e < E) atomicAdd(&deg[dst[e]], 1);
    } else if (b < histB + 773) {
        int bb = b - histB;
        if (bb < 256) {
            // ---- wtrans: WtB[hop][nn][k] = W_upd[hop][k][nn] ----
            int hop = bb >> 6;
            int rem = bb & 63;
            int k0 = (rem & 7) * 32, n0 = (rem >> 3) * 32;
            const float* src = Wu + (size_t)hop * 512 * 256;
            unsigned short* dstp = WtB + (size_t)hop * 256 * 256;
            int tr = t >> 5, tc = t & 31;
#pragma unroll
            for (int r = 0; r < 4; ++r) {
                int k = tr + r * 8;
                T[tc][k] = src[(size_t)(k0 + k) * 256 + n0 + tc];
            }
            __syncthreads();
#pragma unroll
            for (int r = 0; r < 4; ++r) {
                int nn = tr + r * 8;
                dstp[(size_t)(n0 + nn) * 256 + k0 + tc] = f2b(T[nn][tc]);
            }
        } else if (bb < 260) {
            int hop = bb - 256;
            sb[t] = bm[hop * 256 + t];
            __syncthreads();
            const float* B = Wu + (size_t)hop * 512 * 256 + (size_t)256 * 256;
            float acc = 0.f;
#pragma unroll 8
            for (int j = 0; j < 256; ++j) acc += sb[j] * B[(size_t)j * 256 + t];
            cvec[hop * 256 + t] = acc;
        } else if (bb == 260) {
            geInt[t] = 0;
            h8row[t] = 0;
        } else if (bb < 517) {
            // ---- Am: flat fp32->bf16 of W_msg ----
            size_t base = (size_t)(bb - 261) * 2048 + (size_t)t * 8;
            float4 a0 = *(const float4*)(Wm + base);
            float4 a1 = *(const float4*)(Wm + base + 4);
            ushort4 o0, o1;
            o0.x = f2b(a0.x); o0.y = f2b(a0.y); o0.z = f2b(a0.z); o0.w = f2b(a0.w);
            o1.x = f2b(a1.x); o1.y = f2b(a1.y); o1.z = f2b(a1.z); o1.w = f2b(a1.w);
            *(ushort4*)(Am + base) = o0;
            *(ushort4*)(Am + base + 4) = o1;
        } else {
            // ---- BmT: BmT[hop][nn][j] = bf16(Wu2[hop][j][nn]) ----
            int tb = bb - 517;
            int hop = tb >> 6;
            int rem = tb & 63;
            int j0 = (rem & 7) * 32, n0 = (rem >> 3) * 32;
            const float* srcp = Wu + (size_t)hop * 512 * 256 + (size_t)256 * 256;
            unsigned short* dstp = BmT + (size_t)hop * 256 * 256;
            int tr = t >> 5, tc = t & 31;
#pragma unroll
            for (int r = 0; r < 4; ++r) {
                int j = tr + r * 8;
                T[tc][j] = srcp[(size_t)(j0 + j) * 256 + n0 + tc];
            }
            __syncthreads();
#pragma unroll
            for (int r = 0; r < 4; ++r) {
                int nn = tr + r * 8;
                dstp[(size_t)(n0 + nn) * 256 + j0 + tc] = f2b(T[nn][tc]);
            }
        }
    } else {
        // ---- init_h, NPB nodes per block ----
        int v0 = (b - histB - 773) * NPB;
        {
            int j = t >> 5, f = t & 31;
            int v = v0 + j;
            sb[t] = (v < n) ? nodes[(size_t)v * FDIM + f] : 0.f;
        }
        __syncthreads();
        float acc[NPB];
#pragma unroll
        for (int j = 0; j < NPB; ++j) {
            int v = v0 + j;
            acc[j] = (v < n) ? (b_proj[t] + type_emb[(size_t)node_types[v] * NDIM + t]) : 0.f;
        }
#pragma unroll 4
        for (int k = 0; k < FDIM; ++k) {
            float wv = W_proj[(size_t)k * NDIM + t];
#pragma unroll
            for (int j = 0; j < NPB; ++j)
                acc[j] += sb[j * FDIM + k] * wv;
        }
#pragma unroll
        for (int j = 0; j < NPB; ++j) {
            int v = v0 + j;
            if (v < n) {
                h[(size_t)v * NDIM + t] = f2b(acc[j]);
                h8[(size_t)v * NDIM + t] = f2fp8(acc[j]);
            }
        }
    }
}

// ---------- scan phase 1 (blocks 0..nch-1) + mm via MFMA (blocks nch..nch+7) ----------
__global__ __launch_bounds__(1024) void scan1_mm_kernel(
        const int* __restrict__ deg, int* __restrict__ rowptr,
        int* __restrict__ bsum, int nch, int n,
        const unsigned short* __restrict__ Am, const unsigned short* __restrict__ BmT,
        unsigned short* __restrict__ WtA, unsigned short* __restrict__ WtC) {
    int t = threadIdx.x;
    int b = blockIdx.x;
    if (b < nch) {
        __shared__ int wsum[16];
        int i = b * 1024 + t;
        int v = 0;
        if (i < n) v = (deg[i] + 7) & ~7;
        int lane = t & 63, wid = t >> 6;
        int x = v;
#pragma unroll
        for (int d = 1; d < 64; d <<= 1) {
            int u = __shfl_up(x, d, 64);
            if (lane >= d) x += u;
        }
        if (lane == 63) wsum[wid] = x;
        __syncthreads();
        if (wid == 0) {
            int ws = (lane < 16) ? wsum[lane] : 0;
#pragma unroll
            for (int d = 1; d < 16; d <<= 1) {
                int u = __shfl_up(ws, d, 64);
                if (lane >= d) ws += u;
            }
            if (lane < 16) wsum[lane] = ws;
        }
        __syncthreads();
        int excl = (wid > 0 ? wsum[wid - 1] : 0) + x - v;
        if (i < n) rowptr[i] = excl;
        if (t == 1023) bsum[b] = wsum[15];
        return;
    }

    // ---- MFMA mm, all-bf16 operands ----
    int m = b - nch;
    int hop = m >> 1, which = m & 1;
    const unsigned short* A = Am + (size_t)m * 65536;
    const unsigned short* B = BmT + (size_t)hop * 65536;
    unsigned short* W = (which ? WtC : WtA) + (size_t)hop * 65536;
    int wave = t >> 6, lane = t & 63;
    int l16 = lane & 15, quad = lane >> 4;
    int k0 = (wave & 3) * 64;
    int n0 = (wave >> 2) * 64;
    f32x4 acc[4][4];
#pragma unroll
    for (int i = 0; i < 4; ++i)
#pragma unroll
        for (int j = 0; j < 4; ++j) acc[i][j] = (f32x4)(0.f);

    for (int j0 = 0; j0 < 256; j0 += 32) {
        short8 af[4], bfr[4];
#pragma unroll
        for (int kt = 0; kt < 4; ++kt)
            af[kt] = *(const short8*)(A + (size_t)(k0 + kt * 16 + l16) * 256 + j0 + quad * 8);
#pragma unroll
        for (int nt = 0; nt < 4; ++nt)
            bfr[nt] = *(const short8*)(B + (size_t)(n0 + nt * 16 + l16) * 256 + j0 + quad * 8);
#pragma unroll
        for (int kt = 0; kt < 4; ++kt)
#pragma unroll
            for (int nt = 0; nt < 4; ++nt)
                acc[kt][nt] = __builtin_amdgcn_mfma_f32_16x16x32_bf16(af[kt], bfr[nt], acc[kt][nt], 0, 0, 0);
    }
#pragma unroll
    for (int kt = 0; kt < 4; ++kt)
#pragma unroll
        for (int nt = 0; nt < 4; ++nt) {
            int k = k0 + kt * 16 + quad * 4;
            int nn = n0 + nt * 16 + l16;
            ushort4 o;
            o.x = f2b(acc[kt][nt][0]); o.y = f2b(acc[kt][nt][1]);
            o.z = f2b(acc[kt][nt][2]); o.w = f2b(acc[kt][nt][3]);
            *(ushort4*)&W[(size_t)nn * 256 + k] = o;
        }
}

// ---------- scan phase 2 ----------
__global__ __launch_bounds__(1024) void scan2_kernel(
        int* __restrict__ rowptr, int* __restrict__ cursor,
        const int* __restrict__ bsum, int nch, int n) {
    __shared__ int soff, stot;
    int t = threadIdx.x;
    int b = blockIdx.x;
    if (t < 64) {
        int s = (t < nch) ? bsum[t] : 0;
        int x = s;
#pragma unroll
        for (int d = 1; d < 64; d <<= 1) {
            int u = __shfl_up(x, d, 64);
            if (t >= d) x += u;
        }
        if (t == 63) stot = x;
        if (t == b) soff = x - s;
    }
    __syncthreads();
    int i = b * 1024 + t;
    if (i < n) {
        int r = rowptr[i] + soff;
        rowptr[i] = r;
        cursor[i] = r;
    }
    if (b == 0 && t == 0) rowptr[n] = stot;
}

// ---------- fill + pad ----------
__global__ void fillpad_kernel(const int* __restrict__ src, const int* __restrict__ dst,
                               int* __restrict__ cursor,
                               const int* __restrict__ rowptr, const int* __restrict__ deg,
                               int* __restrict__ col, int E, int fillB, int n) {
    int b = blockIdx.x;
    int t = threadIdx.x;
    if (b < fillB) {
        int e = b * 256 + t;
        if (e < E) {
            int d = dst[e];
            int p = atomicAdd(&cursor[d], 1);
            col[p] = src[e];
        }
    } else {
        int v = (b - fillB) * 256 + t;
        if (v < n) {
            int s = rowptr[v] + deg[v];
            int e0 = rowptr[v + 1];
            for (int i = s; i < e0; ++i) col[i] = n;
        }
    }
}

// ---------- neighbor sum: R3/R4 measured-good single-pass version ----------
__global__ __launch_bounds__(256) void agg_kernel(const unsigned char* __restrict__ h8,
                                                  const int* __restrict__ rowptr,
                                                  const int* __restrict__ col,
                                                  unsigned short* __restrict__ S, int n) {
    int wave = threadIdx.x >> 6;
    int lane = threadIdx.x & 63;
    int half = lane >> 5;
    int hl = lane & 31;
    int v = blockIdx.x * 8 + wave * 2 + half;
    if (v >= n) return;
    int beg = rowptr[v], end = rowptr[v + 1];
    float a[8];
#pragma unroll
    for (int e = 0; e < 8; ++e) a[e] = 0.f;
    int cofs = hl * 8;
    for (int i = beg; i < end; i += 8) {
        int cc[8];
#pragma unroll
        for (int j = 0; j < 8; ++j) cc[j] = col[i + j];
        uint2 x[8];
#pragma unroll
        for (int j = 0; j < 8; ++j)
            x[j] = *(const uint2*)(h8 + (size_t)cc[j] * NDIM + cofs);
#pragma unroll
        for (int j = 0; j < 8; ++j) {
            f32x2 p0 = __builtin_amdgcn_cvt_pk_f32_fp8(x[j].x, false);
            f32x2 p1 = __builtin_amdgcn_cvt_pk_f32_fp8(x[j].x, true);
            f32x2 p2 = __builtin_amdgcn_cvt_pk_f32_fp8(x[j].y, false);
            f32x2 p3 = __builtin_amdgcn_cvt_pk_f32_fp8(x[j].y, true);
            a[0] += p0[0]; a[1] += p0[1]; a[2] += p1[0]; a[3] += p1[1];
            a[4] += p2[0]; a[5] += p2[1]; a[6] += p3[0]; a[7] += p3[1];
        }
    }
    uint4 o;
    unsigned short* op = (unsigned short*)&o;
#pragma unroll
    for (int e = 0; e < 8; ++e) op[e] = f2b(a[e]);
    *(uint4*)&S[(size_t)v * NDIM + cofs] = o;
}

// ---------- fused hop GEMM: BM=128 BN=64 BK=64, global_load_lds staging + XOR swizzle ----------
// LDS is UNPADDED [rows][64] (gload_lds needs linear dest). Bank conflicts on the
// ds_read_b128 side are fixed by XOR-ing the 16B col-block with (row&7) (T2), and the
// SOURCE global address is pre-swizzled with the same XOR (G21 both-sides rule):
//   physical block pb = c&7 holds logical block cb = pb ^ (row&7).
// Read: logical block cb -> physical cb ^ (row&7). <=2-way conflicts (free, m136).
#define BM 128
#define BN 64
#define BK 64

template <bool LAST>
__global__ __launch_bounds__(256) void gemm_hop_kernel(const unsigned short* __restrict__ S,
                                                       const unsigned short* __restrict__ hcur,
                                                       const int* __restrict__ deg,
                                                       const unsigned short* __restrict__ WtA,
                                                       const unsigned short* __restrict__ WtB,
                                                       const unsigned short* __restrict__ WtC,
                                                       const float* __restrict__ bupd,
                                                       const float* __restrict__ cvec,
                                                       unsigned short* __restrict__ Out,
                                                       unsigned char* __restrict__ Out8,
                                                       int* __restrict__ geInt, int n) {
    __shared__ unsigned short As[BM * BK];   // 16KB
    __shared__ unsigned short Bs[BN * BK];   // 8KB
    __shared__ unsigned short Cs[BN * BK];   // 8KB
    __shared__ int smax[BN];
    int t = threadIdx.x;
    int lane = t & 63;
    int w = t >> 6;
    int wm = w >> 1, wn = w & 1;
    int quad = lane >> 4, l16 = lane & 15;
    int row0 = blockIdx.x * BM;
    int n0 = blockIdx.y * BN;

    if (LAST) {
        if (t < BN) smax[t] = 0;
    }

    f32x4 acc1[4][2], acc2[4][2];
#pragma unroll
    for (int i = 0; i < 4; ++i)
#pragma unroll
        for (int j = 0; j < 2; ++j) { acc1[i][j] = (f32x4)(0.f); acc2[i][j] = (f32x4)(0.f); }

    // phase 1: acc1 += S @ M1^T
    for (int k0 = 0; k0 < NDIM; k0 += BK) {
        __syncthreads();
#pragma unroll
        for (int h2 = 0; h2 < 4; ++h2) {
            int c = t + h2 * 256;
            int r = c >> 3;
            int cb = (c & 7) ^ (r & 7);          // pre-swizzled logical block
            int grow = row0 + r; if (grow >= n) grow = n - 1;
            __builtin_amdgcn_global_load_lds(
                (const unsigned int*)(S + (size_t)grow * NDIM + k0 + cb * 8),
                (unsigned int*)(As + (size_t)(h2 * 256 + w * 64) * 8), 16, 0, 0);
        }
#pragma unroll
        for (int h2 = 0; h2 < 2; ++h2) {
            int c = t + h2 * 256;
            int r = c >> 3;
            int cb = (c & 7) ^ (r & 7);
            __builtin_amdgcn_global_load_lds(
                (const unsigned int*)(WtA + (size_t)(n0 + r) * NDIM + k0 + cb * 8),
                (unsigned int*)(Bs + (size_t)(h2 * 256 + w * 64) * 8), 16, 0, 0);
        }
        __syncthreads();
#pragma unroll
        for (int ks = 0; ks < BK; ks += 32) {
            short8 af[4], bf[2];
#pragma unroll
            for (int mt = 0; mt < 4; ++mt) {
                int ar = wm * 64 + mt * 16 + l16;
                int acb = ((ks >> 3) + quad) ^ (ar & 7);
                af[mt] = *(const short8*)&As[ar * BK + acb * 8];
            }
#pragma unroll
            for (int nt = 0; nt < 2; ++nt) {
                int br = wn * 32 + nt * 16 + l16;
                int bcb = ((ks >> 3) + quad) ^ (br & 7);
                bf[nt] = *(const short8*)&Bs[br * BK + bcb * 8];
            }
#pragma unroll
            for (int mt = 0; mt < 4; ++mt)
#pragma unroll
                for (int nt = 0; nt < 2; ++nt)
                    acc1[mt][nt] = __builtin_amdgcn_mfma_f32_16x16x32_bf16(af[mt], bf[nt], acc1[mt][nt], 0, 0, 0);
        }
    }
    // phase 2: acc1 += h @ Wu1^T ; acc2 += h @ M2^T
    for (int k0 = 0; k0 < NDIM; k0 += BK) {
        __syncthreads();
#pragma unroll
        for (int h2 = 0; h2 < 4; ++h2) {
            int c = t + h2 * 256;
            int r = c >> 3;
            int cb = (c & 7) ^ (r & 7);
            int grow = row0 + r; if (grow >= n) grow = n - 1;
            __builtin_amdgcn_global_load_lds(
                (const unsigned int*)(hcur + (size_t)grow * NDIM + k0 + cb * 8),
                (unsigned int*)(As + (size_t)(h2 * 256 + w * 64) * 8), 16, 0, 0);
        }
#pragma unroll
        for (int h2 = 0; h2 < 2; ++h2) {
            int c = t + h2 * 256;
            int r = c >> 3;
            int cb = (c & 7) ^ (r & 7);
            size_t widx = (size_t)(n0 + r) * NDIM + k0 + cb * 8;
            __builtin_amdgcn_global_load_lds(
                (const unsigned int*)(WtB + widx),
                (unsigned int*)(Bs + (size_t)(h2 * 256 + w * 64) * 8), 16, 0, 0);
            __builtin_amdgcn_global_load_lds(
                (const unsigned int*)(WtC + widx),
                (unsigned int*)(Cs + (size_t)(h2 * 256 + w * 64) * 8), 16, 0, 0);
        }
        __syncthreads();
#pragma unroll
        for (int ks = 0; ks < BK; ks += 32) {
            short8 af[4], bf[2], cf[2];
#pragma unroll
            for (int mt = 0; mt < 4; ++mt) {
                int ar = wm * 64 + mt * 16 + l16;
                int acb = ((ks >> 3) + quad) ^ (ar & 7);
                af[mt] = *(const short8*)&As[ar * BK + acb * 8];
            }
#pragma unroll
            for (int nt = 0; nt < 2; ++nt) {
                int br = wn * 32 + nt * 16 + l16;
                int bcb = ((ks >> 3) + quad) ^ (br & 7);
                bf[nt] = *(const short8*)&Bs[br * BK + bcb * 8];
                cf[nt] = *(const short8*)&Cs[br * BK + bcb * 8];
            }
#pragma unroll
            for (int mt = 0; mt < 4; ++mt)
#pragma unroll
                for (int nt = 0; nt < 2; ++nt) {
                    acc1[mt][nt] = __builtin_amdgcn_mfma_f32_16x16x32_bf16(af[mt], bf[nt], acc1[mt][nt], 0, 0, 0);
                    acc2[mt][nt] = __builtin_amdgcn_mfma_f32_16x16x32_bf16(af[mt], cf[nt], acc2[mt][nt], 0, 0, 0);
                }
        }
    }
    // epilogue
#pragma unroll
    for (int mt = 0; mt < 4; ++mt) {
#pragma unroll
        for (int nt = 0; nt < 2; ++nt) {
            int lcol = wn * 32 + nt * 16 + l16;
            int col = n0 + lcol;
            float bu = bupd[col];
            float cv = cvec[col];
            float cmax = 0.f;
#pragma unroll
            for (int r = 0; r < 4; ++r) {
                int row = row0 + wm * 64 + mt * 16 + quad * 4 + r;
                if (row < n) {
                    float dg = (float)deg[row];
                    float v = fmaxf(acc1[mt][nt][r] + dg * (acc2[mt][nt][r] + cv) + bu, 0.f);
                    Out[(size_t)row * NDIM + col] = f2b(v);
                    if (!LAST) Out8[(size_t)row * NDIM + col] = f2fp8(v);
                    if (LAST) cmax = fmaxf(cmax, v);
                }
            }
            if (LAST) atomicMax(&smax[lcol], __float_as_int(cmax));
        }
    }
    if (LAST) {
        __syncthreads();
        if (t < BN) atomicMax(&geInt[n0 + t], smax[t]);
    }
}

// ---------- final ----------
__global__ __launch_bounds__(1024) void out_kernel(const float* __restrict__ ge,
                                                   const float* __restrict__ W_out,
                                                   const float* __restrict__ b_out,
                                                   float* __restrict__ out) {
    __shared__ float red[4][NDIM];
    int t = threadIdx.x & 255;
    int g = threadIdx.x >> 8;
    float acc = 0.f;
#pragma unroll 8
    for (int kk = 0; kk < 64; ++kk) {
        int k = g * 64 + kk;
        acc += ge[k] * W_out[k * NDIM + t];
    }
    red[g][t] = acc;
    __syncthreads();
    if (g == 0)
        out[t] = b_out[t] + red[0][t] + red[1][t] + red[2][t] + red[3][t];
}

// ---------- launch ----------
extern "C" void kernel_launch(void* const* d_in, const int* in_sizes, int n_in,
                              void* d_out, int out_size, void* d_ws, size_t ws_size,
                              hipStream_t stream) {
    const float* nodes      = (const float*)d_in[0];
    const int*   edges      = (const int*)d_in[1];
    const int*   node_types = (const int*)d_in[2];
    const float* type_emb   = (const float*)d_in[3];
    const float* W_proj     = (const float*)d_in[4];
    const float* b_proj     = (const float*)d_in[5];
    const float* W_msg      = (const float*)d_in[6];
    const float* b_msg      = (const float*)d_in[7];
    const float* W_upd      = (const float*)d_in[8];
    const float* b_upd      = (const float*)d_in[9];
    const float* W_out      = (const float*)d_in[10];
    const float* b_out      = (const float*)d_in[11];

    int n = in_sizes[2];
    int E = in_sizes[1] / 2;
    const int* src = edges;
    const int* dst = edges + E;

    size_t off = 0;
    auto alloc = [&](size_t bytes) {
        void* p = (char*)d_ws + off;
        off += (bytes + 255) & ~(size_t)255;
        return p;
    };
    int* deg    = (int*)alloc((size_t)(n + 4096) * 4);
    int* rowptr = (int*)alloc((size_t)(n + 1) * 4);
    int* cursor = (int*)alloc((size_t)n * 4);
    int* bsum   = (int*)alloc((size_t)256 * 4);
    int* col    = (int*)alloc((size_t)(E + 8 * n) * 4);
    unsigned short* WtA = (unsigned short*)alloc((size_t)HOPS * 256 * 256 * 2);
    unsigned short* WtB = (unsigned short*)alloc((size_t)HOPS * 256 * 256 * 2);
    unsigned short* WtC = (unsigned short*)alloc((size_t)HOPS * 256 * 256 * 2);
    unsigned short* Am  = (unsigned short*)alloc((size_t)8 * 256 * 256 * 2);
    unsigned short* BmT = (unsigned short*)alloc((size_t)HOPS * 256 * 256 * 2);
    float* cvec = (float*)alloc((size_t)HOPS * 256 * 4);
    int* geInt  = (int*)alloc((size_t)256 * 4);
    unsigned short* hA  = (unsigned short*)alloc((size_t)(n + 1) * NDIM * 2);
    unsigned short* hB  = (unsigned short*)alloc((size_t)(n + 1) * NDIM * 2);
    unsigned short* Sb  = (unsigned short*)alloc((size_t)n * NDIM * 2);
    unsigned char* h8   = (unsigned char*)alloc((size_t)(n + 1) * NDIM);

    hipMemsetAsync(deg, 0, (size_t)(n + 4096) * 4, stream);
    int eb = (E + 255) / 256;
    int pb = (n + 255) / 256;
    int ib = (n + NPB - 1) / NPB;
    int nch = (n + 1023) / 1024;
    prep_mega_kernel<<<eb + 773 + ib, 256, 0, stream>>>(
        dst, deg, E, eb,
        W_msg, W_upd, b_msg, WtB, Am, BmT, cvec, geInt, h8 + (size_t)n * NDIM,
        nodes, node_types, type_emb, W_proj, b_proj, hA, h8, n);
    scan1_mm_kernel<<<nch + 8, 1024, 0, stream>>>(deg, rowptr, bsum, nch, n, Am, BmT, WtA, WtC);
    scan2_kernel<<<nch, 1024, 0, stream>>>(rowptr, cursor, bsum, nch, n);
    fillpad_kernel<<<eb + pb, 256, 0, stream>>>(src, dst, cursor, rowptr, deg, col, E, eb, n);

    unsigned short* h  = hA;
    unsigned short* ho = hB;
    int gx = (n + BM - 1) / BM;
    dim3 ggrid(gx, NDIM / BN);
    for (int i = 0; i < HOPS; ++i) {
        agg_kernel<<<(n + 7) / 8, 256, 0, stream>>>(h8, rowptr, col, Sb, n);
        size_t wofs = (size_t)i * 256 * 256;
        if (i == HOPS - 1)
            gemm_hop_kernel<true><<<ggrid, 256, 0, stream>>>(
                Sb, h, deg, WtA + wofs, WtB + wofs, WtC + wofs,
                b_upd + (size_t)i * NDIM, cvec + (size_t)i * NDIM, ho, h8, geInt, n);
        else
            gemm_hop_kernel<false><<<ggrid, 256, 0, stream>>>(
                Sb, h, deg, WtA + wofs, WtB + wofs, WtC + wofs,
                b_upd + (size_t)i * NDIM, cvec + (size_t)i * NDIM, ho, h8, geInt, n);
        unsigned short* tmp = h; h = ho; ho = tmp;
    }
    out_kernel<<<1, 1024, 0, stream>>>((const float*)geInt, W_out, b_out, (float*)d_out);
}

// Round 7
// 334.784 us; speedup vs baseline: 1.1772x; 1.0919x over previous
//
#include <hip/hip_runtime.h>
#include <hip/hip_bf16.h>

#define NDIM 256
#define FDIM 32
#define HOPS 4
#define NPB 8   // nodes per init block

typedef __attribute__((ext_vector_type(8))) short short8;
typedef __attribute__((ext_vector_type(4))) float f32x4;
typedef __attribute__((ext_vector_type(2))) float f32x2;

// ---------- helpers ----------
__device__ inline float b2f(unsigned short u) {
    union { unsigned int i; float f; } v; v.i = ((unsigned int)u) << 16; return v.f;
}
__device__ inline unsigned short f2b(float f) {
    union { float f; unsigned int i; } v; v.f = f;
    unsigned int r = v.i + 0x7FFF + ((v.i >> 16) & 1);
    return (unsigned short)(r >> 16);
}
__device__ inline unsigned char f2fp8(float v) {
    return (unsigned char)(__builtin_amdgcn_cvt_pk_fp8_f32(v, v, 0, false) & 0xFF);
}

// ---------- prep mega ----------
__global__ __launch_bounds__(256) void prep_mega_kernel(
        const int* __restrict__ dst, int* __restrict__ deg, int E, int histB,
        const float* __restrict__ Wm, const float* __restrict__ Wu,
        const float* __restrict__ bm,
        unsigned short* __restrict__ WtB,
        unsigned short* __restrict__ Am, unsigned short* __restrict__ BmT,
        float* __restrict__ cvec, int* __restrict__ geInt,
        unsigned char* __restrict__ h8row,
        const float* __restrict__ nodes, const int* __restrict__ node_types,
        const float* __restrict__ type_emb, const float* __restrict__ W_proj,
        const float* __restrict__ b_proj,
        unsigned short* __restrict__ h, unsigned char* __restrict__ h8, int n) {
    __shared__ float T[32][33];
    __shared__ float sb[256];
    int b = blockIdx.x;
    int t = threadIdx.x;

    if (b < histB) {
        int e = b * 256 + t;
        if (e < E) atomicAdd(&deg[dst[e]], 1);
    } else if (b < histB + 773) {
        int bb = b - histB;
        if (bb < 256) {
            // ---- wtrans: WtB[hop][nn][k] = W_upd[hop][k][nn] ----
            int hop = bb >> 6;
            int rem = bb & 63;
            int k0 = (rem & 7) * 32, n0 = (rem >> 3) * 32;
            const float* src = Wu + (size_t)hop * 512 * 256;
            unsigned short* dstp = WtB + (size_t)hop * 256 * 256;
            int tr = t >> 5, tc = t & 31;
#pragma unroll
            for (int r = 0; r < 4; ++r) {
                int k = tr + r * 8;
                T[tc][k] = src[(size_t)(k0 + k) * 256 + n0 + tc];
            }
            __syncthreads();
#pragma unroll
            for (int r = 0; r < 4; ++r) {
                int nn = tr + r * 8;
                dstp[(size_t)(n0 + nn) * 256 + k0 + tc] = f2b(T[nn][tc]);
            }
        } else if (bb < 260) {
            int hop = bb - 256;
            sb[t] = bm[hop * 256 + t];
            __syncthreads();
            const float* B = Wu + (size_t)hop * 512 * 256 + (size_t)256 * 256;
            float acc = 0.f;
#pragma unroll 8
            for (int j = 0; j < 256; ++j) acc += sb[j] * B[(size_t)j * 256 + t];
            cvec[hop * 256 + t] = acc;
        } else if (bb == 260) {
            geInt[t] = 0;
            h8row[t] = 0;
        } else if (bb < 517) {
            // ---- Am: flat fp32->bf16 of W_msg ----
            size_t base = (size_t)(bb - 261) * 2048 + (size_t)t * 8;
            float4 a0 = *(const float4*)(Wm + base);
            float4 a1 = *(const float4*)(Wm + base + 4);
            ushort4 o0, o1;
            o0.x = f2b(a0.x); o0.y = f2b(a0.y); o0.z = f2b(a0.z); o0.w = f2b(a0.w);
            o1.x = f2b(a1.x); o1.y = f2b(a1.y); o1.z = f2b(a1.z); o1.w = f2b(a1.w);
            *(ushort4*)(Am + base) = o0;
            *(ushort4*)(Am + base + 4) = o1;
        } else {
            // ---- BmT: BmT[hop][nn][j] = bf16(Wu2[hop][j][nn]) ----
            int tb = bb - 517;
            int hop = tb >> 6;
            int rem = tb & 63;
            int j0 = (rem & 7) * 32, n0 = (rem >> 3) * 32;
            const float* srcp = Wu + (size_t)hop * 512 * 256 + (size_t)256 * 256;
            unsigned short* dstp = BmT + (size_t)hop * 256 * 256;
            int tr = t >> 5, tc = t & 31;
#pragma unroll
            for (int r = 0; r < 4; ++r) {
                int j = tr + r * 8;
                T[tc][j] = srcp[(size_t)(j0 + j) * 256 + n0 + tc];
            }
            __syncthreads();
#pragma unroll
            for (int r = 0; r < 4; ++r) {
                int nn = tr + r * 8;
                dstp[(size_t)(n0 + nn) * 256 + j0 + tc] = f2b(T[nn][tc]);
            }
        }
    } else {
        // ---- init_h, NPB nodes per block ----
        int v0 = (b - histB - 773) * NPB;
        {
            int j = t >> 5, f = t & 31;
            int v = v0 + j;
            sb[t] = (v < n) ? nodes[(size_t)v * FDIM + f] : 0.f;
        }
        __syncthreads();
        float acc[NPB];
#pragma unroll
        for (int j = 0; j < NPB; ++j) {
            int v = v0 + j;
            acc[j] = (v < n) ? (b_proj[t] + type_emb[(size_t)node_types[v] * NDIM + t]) : 0.f;
        }
#pragma unroll 4
        for (int k = 0; k < FDIM; ++k) {
            float wv = W_proj[(size_t)k * NDIM + t];
#pragma unroll
            for (int j = 0; j < NPB; ++j)
                acc[j] += sb[j * FDIM + k] * wv;
        }
#pragma unroll
        for (int j = 0; j < NPB; ++j) {
            int v = v0 + j;
            if (v < n) {
                h[(size_t)v * NDIM + t] = f2b(acc[j]);
                h8[(size_t)v * NDIM + t] = f2fp8(acc[j]);
            }
        }
    }
}

// ---------- scan phase 1 (blocks 0..nch-1) + mm via MFMA (blocks nch..nch+7) ----------
__global__ __launch_bounds__(1024) void scan1_mm_kernel(
        const int* __restrict__ deg, int* __restrict__ rowptr,
        int* __restrict__ bsum, int nch, int n,
        const unsigned short* __restrict__ Am, const unsigned short* __restrict__ BmT,
        unsigned short* __restrict__ WtA, unsigned short* __restrict__ WtC) {
    int t = threadIdx.x;
    int b = blockIdx.x;
    if (b < nch) {
        __shared__ int wsum[16];
        int i = b * 1024 + t;
        int v = 0;
        if (i < n) v = (deg[i] + 7) & ~7;
        int lane = t & 63, wid = t >> 6;
        int x = v;
#pragma unroll
        for (int d = 1; d < 64; d <<= 1) {
            int u = __shfl_up(x, d, 64);
            if (lane >= d) x += u;
        }
        if (lane == 63) wsum[wid] = x;
        __syncthreads();
        if (wid == 0) {
            int ws = (lane < 16) ? wsum[lane] : 0;
#pragma unroll
            for (int d = 1; d < 16; d <<= 1) {
                int u = __shfl_up(ws, d, 64);
                if (lane >= d) ws += u;
            }
            if (lane < 16) wsum[lane] = ws;
        }
        __syncthreads();
        int excl = (wid > 0 ? wsum[wid - 1] : 0) + x - v;
        if (i < n) rowptr[i] = excl;
        if (t == 1023) bsum[b] = wsum[15];
        return;
    }

    // ---- MFMA mm, all-bf16 operands ----
    int m = b - nch;
    int hop = m >> 1, which = m & 1;
    const unsigned short* A = Am + (size_t)m * 65536;
    const unsigned short* B = BmT + (size_t)hop * 65536;
    unsigned short* W = (which ? WtC : WtA) + (size_t)hop * 65536;
    int wave = t >> 6, lane = t & 63;
    int l16 = lane & 15, quad = lane >> 4;
    int k0 = (wave & 3) * 64;
    int n0 = (wave >> 2) * 64;
    f32x4 acc[4][4];
#pragma unroll
    for (int i = 0; i < 4; ++i)
#pragma unroll
        for (int j = 0; j < 4; ++j) acc[i][j] = (f32x4)(0.f);

    for (int j0 = 0; j0 < 256; j0 += 32) {
        short8 af[4], bfr[4];
#pragma unroll
        for (int kt = 0; kt < 4; ++kt)
            af[kt] = *(const short8*)(A + (size_t)(k0 + kt * 16 + l16) * 256 + j0 + quad * 8);
#pragma unroll
        for (int nt = 0; nt < 4; ++nt)
            bfr[nt] = *(const short8*)(B + (size_t)(n0 + nt * 16 + l16) * 256 + j0 + quad * 8);
#pragma unroll
        for (int kt = 0; kt < 4; ++kt)
#pragma unroll
            for (int nt = 0; nt < 4; ++nt)
                acc[kt][nt] = __builtin_amdgcn_mfma_f32_16x16x32_bf16(af[kt], bfr[nt], acc[kt][nt], 0, 0, 0);
    }
#pragma unroll
    for (int kt = 0; kt < 4; ++kt)
#pragma unroll
        for (int nt = 0; nt < 4; ++nt) {
            int k = k0 + kt * 16 + quad * 4;
            int nn = n0 + nt * 16 + l16;
            ushort4 o;
            o.x = f2b(acc[kt][nt][0]); o.y = f2b(acc[kt][nt][1]);
            o.z = f2b(acc[kt][nt][2]); o.w = f2b(acc[kt][nt][3]);
            *(ushort4*)&W[(size_t)nn * 256 + k] = o;
        }
}

// ---------- scan phase 2 ----------
__global__ __launch_bounds__(1024) void scan2_kernel(
        int* __restrict__ rowptr, int* __restrict__ cursor,
        const int* __restrict__ bsum, int nch, int n) {
    __shared__ int soff, stot;
    int t = threadIdx.x;
    int b = blockIdx.x;
    if (t < 64) {
        int s = (t < nch) ? bsum[t] : 0;
        int x = s;
#pragma unroll
        for (int d = 1; d < 64; d <<= 1) {
            int u = __shfl_up(x, d, 64);
            if (t >= d) x += u;
        }
        if (t == 63) stot = x;
        if (t == b) soff = x - s;
    }
    __syncthreads();
    int i = b * 1024 + t;
    if (i < n) {
        int r = rowptr[i] + soff;
        rowptr[i] = r;
        cursor[i] = r;
    }
    if (b == 0 && t == 0) rowptr[n] = stot;
}

// ---------- fill + pad ----------
__global__ void fillpad_kernel(const int* __restrict__ src, const int* __restrict__ dst,
                               int* __restrict__ cursor,
                               const int* __restrict__ rowptr, const int* __restrict__ deg,
                               int* __restrict__ col, int E, int fillB, int n) {
    int b = blockIdx.x;
    int t = threadIdx.x;
    if (b < fillB) {
        int e = b * 256 + t;
        if (e < E) {
            int d = dst[e];
            int p = atomicAdd(&cursor[d], 1);
            col[p] = src[e];
        }
    } else {
        int v = (b - fillB) * 256 + t;
        if (v < n) {
            int s = rowptr[v] + deg[v];
            int e0 = rowptr[v + 1];
            for (int i = s; i < e0; ++i) col[i] = n;
        }
    }
}

// ---------- neighbor sum: R0 structure with 16-deep MLP main loop + 8-deep tail ----------
// R1/R5 evidence: agg responds to outstanding-gather depth (latency component), not
// request width. Main loop keeps 16 col loads + 16 uint2 gathers in flight (2x R0's
// depth); accumulation order j ascending == two sequential 8-chunks -> bit-exact.
__global__ __launch_bounds__(256) void agg_kernel(const unsigned char* __restrict__ h8,
                                                  const int* __restrict__ rowptr,
                                                  const int* __restrict__ col,
                                                  unsigned short* __restrict__ S, int n) {
    int wave = threadIdx.x >> 6;
    int lane = threadIdx.x & 63;
    int half = lane >> 5;
    int hl = lane & 31;
    int v = blockIdx.x * 8 + wave * 2 + half;
    if (v >= n) return;
    int beg = rowptr[v], end = rowptr[v + 1];
    float a[8];
#pragma unroll
    for (int e = 0; e < 8; ++e) a[e] = 0.f;
    int cofs = hl * 8;
    int i = beg;
    for (; i + 16 <= end; i += 16) {
        int cc[16];
#pragma unroll
        for (int j = 0; j < 16; ++j) cc[j] = col[i + j];
        uint2 x[16];
#pragma unroll
        for (int j = 0; j < 16; ++j)
            x[j] = *(const uint2*)(h8 + (size_t)cc[j] * NDIM + cofs);
#pragma unroll
        for (int j = 0; j < 16; ++j) {
            f32x2 p0 = __builtin_amdgcn_cvt_pk_f32_fp8(x[j].x, false);
            f32x2 p1 = __builtin_amdgcn_cvt_pk_f32_fp8(x[j].x, true);
            f32x2 p2 = __builtin_amdgcn_cvt_pk_f32_fp8(x[j].y, false);
            f32x2 p3 = __builtin_amdgcn_cvt_pk_f32_fp8(x[j].y, true);
            a[0] += p0[0]; a[1] += p0[1]; a[2] += p1[0]; a[3] += p1[1];
            a[4] += p2[0]; a[5] += p2[1]; a[6] += p3[0]; a[7] += p3[1];
        }
    }
    for (; i < end; i += 8) {
        int cc[8];
#pragma unroll
        for (int j = 0; j < 8; ++j) cc[j] = col[i + j];
        uint2 x[8];
#pragma unroll
        for (int j = 0; j < 8; ++j)
            x[j] = *(const uint2*)(h8 + (size_t)cc[j] * NDIM + cofs);
#pragma unroll
        for (int j = 0; j < 8; ++j) {
            f32x2 p0 = __builtin_amdgcn_cvt_pk_f32_fp8(x[j].x, false);
            f32x2 p1 = __builtin_amdgcn_cvt_pk_f32_fp8(x[j].x, true);
            f32x2 p2 = __builtin_amdgcn_cvt_pk_f32_fp8(x[j].y, false);
            f32x2 p3 = __builtin_amdgcn_cvt_pk_f32_fp8(x[j].y, true);
            a[0] += p0[0]; a[1] += p0[1]; a[2] += p1[0]; a[3] += p1[1];
            a[4] += p2[0]; a[5] += p2[1]; a[6] += p3[0]; a[7] += p3[1];
        }
    }
    uint4 o;
    unsigned short* op = (unsigned short*)&o;
#pragma unroll
    for (int e = 0; e < 8; ++e) op[e] = f2b(a[e]);
    *(uint4*)&S[(size_t)v * NDIM + cofs] = o;
}

// ---------- fused hop GEMM: BM=128 BN=64 BK=64, gload_lds + XOR swizzle ----------
// __launch_bounds__(256, 4): target 4 blocks/CU (VGPR<=128). acc regs = 96; staging
// via global_load_lds needs no data registers, so the bound should hold without spill.
#define BM 128
#define BN 64
#define BK 64

template <bool LAST>
__global__ __launch_bounds__(256, 4) void gemm_hop_kernel(const unsigned short* __restrict__ S,
                                                          const unsigned short* __restrict__ hcur,
                                                          const int* __restrict__ deg,
                                                          const unsigned short* __restrict__ WtA,
                                                          const unsigned short* __restrict__ WtB,
                                                          const unsigned short* __restrict__ WtC,
                                                          const float* __restrict__ bupd,
                                                          const float* __restrict__ cvec,
                                                          unsigned short* __restrict__ Out,
                                                          unsigned char* __restrict__ Out8,
                                                          int* __restrict__ geInt, int n) {
    __shared__ unsigned short As[BM * BK];   // 16KB
    __shared__ unsigned short Bs[BN * BK];   // 8KB
    __shared__ unsigned short Cs[BN * BK];   // 8KB
    __shared__ int smax[BN];
    int t = threadIdx.x;
    int lane = t & 63;
    int w = t >> 6;
    int wm = w >> 1, wn = w & 1;
    int quad = lane >> 4, l16 = lane & 15;
    int row0 = blockIdx.x * BM;
    int n0 = blockIdx.y * BN;

    if (LAST) {
        if (t < BN) smax[t] = 0;
    }

    f32x4 acc1[4][2], acc2[4][2];
#pragma unroll
    for (int i = 0; i < 4; ++i)
#pragma unroll
        for (int j = 0; j < 2; ++j) { acc1[i][j] = (f32x4)(0.f); acc2[i][j] = (f32x4)(0.f); }

    // phase 1: acc1 += S @ M1^T
    for (int k0 = 0; k0 < NDIM; k0 += BK) {
        __syncthreads();
#pragma unroll
        for (int h2 = 0; h2 < 4; ++h2) {
            int c = t + h2 * 256;
            int r = c >> 3;
            int cb = (c & 7) ^ (r & 7);          // pre-swizzled logical block
            int grow = row0 + r; if (grow >= n) grow = n - 1;
            __builtin_amdgcn_global_load_lds(
                (const unsigned int*)(S + (size_t)grow * NDIM + k0 + cb * 8),
                (unsigned int*)(As + (size_t)(h2 * 256 + w * 64) * 8), 16, 0, 0);
        }
#pragma unroll
        for (int h2 = 0; h2 < 2; ++h2) {
            int c = t + h2 * 256;
            int r = c >> 3;
            int cb = (c & 7) ^ (r & 7);
            __builtin_amdgcn_global_load_lds(
                (const unsigned int*)(WtA + (size_t)(n0 + r) * NDIM + k0 + cb * 8),
                (unsigned int*)(Bs + (size_t)(h2 * 256 + w * 64) * 8), 16, 0, 0);
        }
        __syncthreads();
#pragma unroll
        for (int ks = 0; ks < BK; ks += 32) {
            short8 af[4], bf[2];
#pragma unroll
            for (int mt = 0; mt < 4; ++mt) {
                int ar = wm * 64 + mt * 16 + l16;
                int acb = ((ks >> 3) + quad) ^ (ar & 7);
                af[mt] = *(const short8*)&As[ar * BK + acb * 8];
            }
#pragma unroll
            for (int nt = 0; nt < 2; ++nt) {
                int br = wn * 32 + nt * 16 + l16;
                int bcb = ((ks >> 3) + quad) ^ (br & 7);
                bf[nt] = *(const short8*)&Bs[br * BK + bcb * 8];
            }
#pragma unroll
            for (int mt = 0; mt < 4; ++mt)
#pragma unroll
                for (int nt = 0; nt < 2; ++nt)
                    acc1[mt][nt] = __builtin_amdgcn_mfma_f32_16x16x32_bf16(af[mt], bf[nt], acc1[mt][nt], 0, 0, 0);
        }
    }
    // phase 2: acc1 += h @ Wu1^T ; acc2 += h @ M2^T
    for (int k0 = 0; k0 < NDIM; k0 += BK) {
        __syncthreads();
#pragma unroll
        for (int h2 = 0; h2 < 4; ++h2) {
            int c = t + h2 * 256;
            int r = c >> 3;
            int cb = (c & 7) ^ (r & 7);
            int grow = row0 + r; if (grow >= n) grow = n - 1;
            __builtin_amdgcn_global_load_lds(
                (const unsigned int*)(hcur + (size_t)grow * NDIM + k0 + cb * 8),
                (unsigned int*)(As + (size_t)(h2 * 256 + w * 64) * 8), 16, 0, 0);
        }
#pragma unroll
        for (int h2 = 0; h2 < 2; ++h2) {
            int c = t + h2 * 256;
            int r = c >> 3;
            int cb = (c & 7) ^ (r & 7);
            size_t widx = (size_t)(n0 + r) * NDIM + k0 + cb * 8;
            __builtin_amdgcn_global_load_lds(
                (const unsigned int*)(WtB + widx),
                (unsigned int*)(Bs + (size_t)(h2 * 256 + w * 64) * 8), 16, 0, 0);
            __builtin_amdgcn_global_load_lds(
                (const unsigned int*)(WtC + widx),
                (unsigned int*)(Cs + (size_t)(h2 * 256 + w * 64) * 8), 16, 0, 0);
        }
        __syncthreads();
#pragma unroll
        for (int ks = 0; ks < BK; ks += 32) {
            short8 af[4], bf[2], cf[2];
#pragma unroll
            for (int mt = 0; mt < 4; ++mt) {
                int ar = wm * 64 + mt * 16 + l16;
                int acb = ((ks >> 3) + quad) ^ (ar & 7);
                af[mt] = *(const short8*)&As[ar * BK + acb * 8];
            }
#pragma unroll
            for (int nt = 0; nt < 2; ++nt) {
                int br = wn * 32 + nt * 16 + l16;
                int bcb = ((ks >> 3) + quad) ^ (br & 7);
                bf[nt] = *(const short8*)&Bs[br * BK + bcb * 8];
                cf[nt] = *(const short8*)&Cs[br * BK + bcb * 8];
            }
#pragma unroll
            for (int mt = 0; mt < 4; ++mt)
#pragma unroll
                for (int nt = 0; nt < 2; ++nt) {
                    acc1[mt][nt] = __builtin_amdgcn_mfma_f32_16x16x32_bf16(af[mt], bf[nt], acc1[mt][nt], 0, 0, 0);
                    acc2[mt][nt] = __builtin_amdgcn_mfma_f32_16x16x32_bf16(af[mt], cf[nt], acc2[mt][nt], 0, 0, 0);
                }
        }
    }
    // epilogue
#pragma unroll
    for (int mt = 0; mt < 4; ++mt) {
#pragma unroll
        for (int nt = 0; nt < 2; ++nt) {
            int lcol = wn * 32 + nt * 16 + l16;
            int col = n0 + lcol;
            float bu = bupd[col];
            float cv = cvec[col];
            float cmax = 0.f;
#pragma unroll
            for (int r = 0; r < 4; ++r) {
                int row = row0 + wm * 64 + mt * 16 + quad * 4 + r;
                if (row < n) {
                    float dg = (float)deg[row];
                    float v = fmaxf(acc1[mt][nt][r] + dg * (acc2[mt][nt][r] + cv) + bu, 0.f);
                    Out[(size_t)row * NDIM + col] = f2b(v);
                    if (!LAST) Out8[(size_t)row * NDIM + col] = f2fp8(v);
                    if (LAST) cmax = fmaxf(cmax, v);
                }
            }
            if (LAST) atomicMax(&smax[lcol], __float_as_int(cmax));
        }
    }
    if (LAST) {
        __syncthreads();
        if (t < BN) atomicMax(&geInt[n0 + t], smax[t]);
    }
}

// ---------- final ----------
__global__ __launch_bounds__(1024) void out_kernel(const float* __restrict__ ge,
                                                   const float* __restrict__ W_out,
                                                   const float* __restrict__ b_out,
                                                   float* __restrict__ out) {
    __shared__ float red[4][NDIM];
    int t = threadIdx.x & 255;
    int g = threadIdx.x >> 8;
    float acc = 0.f;
#pragma unroll 8
    for (int kk = 0; kk < 64; ++kk) {
        int k = g * 64 + kk;
        acc += ge[k] * W_out[k * NDIM + t];
    }
    red[g][t] = acc;
    __syncthreads();
    if (g == 0)
        out[t] = b_out[t] + red[0][t] + red[1][t] + red[2][t] + red[3][t];
}

// ---------- launch ----------
extern "C" void kernel_launch(void* const* d_in, const int* in_sizes, int n_in,
                              void* d_out, int out_size, void* d_ws, size_t ws_size,
                              hipStream_t stream) {
    const float* nodes      = (const float*)d_in[0];
    const int*   edges      = (const int*)d_in[1];
    const int*   node_types = (const int*)d_in[2];
    const float* type_emb   = (const float*)d_in[3];
    const float* W_proj     = (const float*)d_in[4];
    const float* b_proj     = (const float*)d_in[5];
    const float* W_msg      = (const float*)d_in[6];
    const float* b_msg      = (const float*)d_in[7];
    const float* W_upd      = (const float*)d_in[8];
    const float* b_upd      = (const float*)d_in[9];
    const float* W_out      = (const float*)d_in[10];
    const float* b_out      = (const float*)d_in[11];

    int n = in_sizes[2];
    int E = in_sizes[1] / 2;
    const int* src = edges;
    const int* dst = edges + E;

    size_t off = 0;
    auto alloc = [&](size_t bytes) {
        void* p = (char*)d_ws + off;
        off += (bytes + 255) & ~(size_t)255;
        return p;
    };
    int* deg    = (int*)alloc((size_t)(n + 4096) * 4);
    int* rowptr = (int*)alloc((size_t)(n + 1) * 4);
    int* cursor = (int*)alloc((size_t)n * 4);
    int* bsum   = (int*)alloc((size_t)256 * 4);
    int* col    = (int*)alloc((size_t)(E + 8 * n) * 4);
    unsigned short* WtA = (unsigned short*)alloc((size_t)HOPS * 256 * 256 * 2);
    unsigned short* WtB = (unsigned short*)alloc((size_t)HOPS * 256 * 256 * 2);
    unsigned short* WtC = (unsigned short*)alloc((size_t)HOPS * 256 * 256 * 2);
    unsigned short* Am  = (unsigned short*)alloc((size_t)8 * 256 * 256 * 2);
    unsigned short* BmT = (unsigned short*)alloc((size_t)HOPS * 256 * 256 * 2);
    float* cvec = (float*)alloc((size_t)HOPS * 256 * 4);
    int* geInt  = (int*)alloc((size_t)256 * 4);
    unsigned short* hA  = (unsigned short*)alloc((size_t)(n + 1) * NDIM * 2);
    unsigned short* hB  = (unsigned short*)alloc((size_t)(n + 1) * NDIM * 2);
    unsigned short* Sb  = (unsigned short*)alloc((size_t)n * NDIM * 2);
    unsigned char* h8   = (unsigned char*)alloc((size_t)(n + 1) * NDIM);

    hipMemsetAsync(deg, 0, (size_t)(n + 4096) * 4, stream);
    int eb = (E + 255) / 256;
    int pb = (n + 255) / 256;
    int ib = (n + NPB - 1) / NPB;
    int nch = (n + 1023) / 1024;
    prep_mega_kernel<<<eb + 773 + ib, 256, 0, stream>>>(
        dst, deg, E, eb,
        W_msg, W_upd, b_msg, WtB, Am, BmT, cvec, geInt, h8 + (size_t)n * NDIM,
        nodes, node_types, type_emb, W_proj, b_proj, hA, h8, n);
    scan1_mm_kernel<<<nch + 8, 1024, 0, stream>>>(deg, rowptr, bsum, nch, n, Am, BmT, WtA, WtC);
    scan2_kernel<<<nch, 1024, 0, stream>>>(rowptr, cursor, bsum, nch, n);
    fillpad_kernel<<<eb + pb, 256, 0, stream>>>(src, dst, cursor, rowptr, deg, col, E, eb, n);

    unsigned short* h  = hA;
    unsigned short* ho = hB;
    int gx = (n + BM - 1) / BM;
    dim3 ggrid(gx, NDIM / BN);
    for (int i = 0; i < HOPS; ++i) {
        agg_kernel<<<(n + 7) / 8, 256, 0, stream>>>(h8, rowptr, col, Sb, n);
        size_t wofs = (size_t)i * 256 * 256;
        if (i == HOPS - 1)
            gemm_hop_kernel<true><<<ggrid, 256, 0, stream>>>(
                Sb, h, deg, WtA + wofs, WtB + wofs, WtC + wofs,
                b_upd + (size_t)i * NDIM, cvec + (size_t)i * NDIM, ho, h8, geInt, n);
        else
            gemm_hop_kernel<false><<<ggrid, 256, 0, stream>>>(
                Sb, h, deg, WtA + wofs, WtB + wofs, WtC + wofs,
                b_upd + (size_t)i * NDIM, cvec + (size_t)i * NDIM, ho, h8, geInt, n);
        unsigned short* tmp = h; h = ho; ho = tmp;
    }
    out_kernel<<<1, 1024, 0, stream>>>((const float*)geInt, W_out, b_out, (float*)d_out);
}

// Round 8
// 332.181 us; speedup vs baseline: 1.1864x; 1.0078x over previous
//
#include <hip/hip_runtime.h>
#include <hip/hip_bf16.h>

#define NDIM 256
#define FDIM 32
#define HOPS 4
#define NPB 8   // nodes per init block

typedef __attribute__((ext_vector_type(8))) short short8;
typedef __attribute__((ext_vector_type(4))) float f32x4;
typedef __attribute__((ext_vector_type(2))) float f32x2;

// ---------- helpers ----------
__device__ inline float b2f(unsigned short u) {
    union { unsigned int i; float f; } v; v.i = ((unsigned int)u) << 16; return v.f;
}
__device__ inline unsigned short f2b(float f) {
    union { float f; unsigned int i; } v; v.f = f;
    unsigned int r = v.i + 0x7FFF + ((v.i >> 16) & 1);
    return (unsigned short)(r >> 16);
}
__device__ inline unsigned char f2fp8(float v) {
    return (unsigned char)(__builtin_amdgcn_cvt_pk_fp8_f32(v, v, 0, false) & 0xFF);
}

// ---------- prep mega ----------
// hist blocks now process 4 edges/thread via int4 (1563 -> 391 blocks, coalesced 16B
// dst reads; same atomic count, order-independent -> bit-exact).
__global__ __launch_bounds__(256) void prep_mega_kernel(
        const int* __restrict__ dst, int* __restrict__ deg, int E, int histB,
        const float* __restrict__ Wm, const float* __restrict__ Wu,
        const float* __restrict__ bm,
        unsigned short* __restrict__ WtB,
        unsigned short* __restrict__ Am, unsigned short* __restrict__ BmT,
        float* __restrict__ cvec, int* __restrict__ geInt,
        unsigned char* __restrict__ h8row,
        const float* __restrict__ nodes, const int* __restrict__ node_types,
        const float* __restrict__ type_emb, const float* __restrict__ W_proj,
        const float* __restrict__ b_proj,
        unsigned short* __restrict__ h, unsigned char* __restrict__ h8, int n) {
    __shared__ float T[32][33];
    __shared__ float sb[256];
    int b = blockIdx.x;
    int t = threadIdx.x;

    if (b < histB) {
        int e = (b * 256 + t) * 4;
        if (e + 3 < E) {
            int4 d = *(const int4*)(dst + e);
            atomicAdd(&deg[d.x], 1);
            atomicAdd(&deg[d.y], 1);
            atomicAdd(&deg[d.z], 1);
            atomicAdd(&deg[d.w], 1);
        } else {
            for (int k = e; k < E; ++k) atomicAdd(&deg[dst[k]], 1);
        }
    } else if (b < histB + 773) {
        int bb = b - histB;
        if (bb < 256) {
            // ---- wtrans: WtB[hop][nn][k] = W_upd[hop][k][nn] ----
            int hop = bb >> 6;
            int rem = bb & 63;
            int k0 = (rem & 7) * 32, n0 = (rem >> 3) * 32;
            const float* src = Wu + (size_t)hop * 512 * 256;
            unsigned short* dstp = WtB + (size_t)hop * 256 * 256;
            int tr = t >> 5, tc = t & 31;
#pragma unroll
            for (int r = 0; r < 4; ++r) {
                int k = tr + r * 8;
                T[tc][k] = src[(size_t)(k0 + k) * 256 + n0 + tc];
            }
            __syncthreads();
#pragma unroll
            for (int r = 0; r < 4; ++r) {
                int nn = tr + r * 8;
                dstp[(size_t)(n0 + nn) * 256 + k0 + tc] = f2b(T[nn][tc]);
            }
        } else if (bb < 260) {
            int hop = bb - 256;
            sb[t] = bm[hop * 256 + t];
            __syncthreads();
            const float* B = Wu + (size_t)hop * 512 * 256 + (size_t)256 * 256;
            float acc = 0.f;
#pragma unroll 8
            for (int j = 0; j < 256; ++j) acc += sb[j] * B[(size_t)j * 256 + t];
            cvec[hop * 256 + t] = acc;
        } else if (bb == 260) {
            geInt[t] = 0;
            h8row[t] = 0;
        } else if (bb < 517) {
            // ---- Am: flat fp32->bf16 of W_msg ----
            size_t base = (size_t)(bb - 261) * 2048 + (size_t)t * 8;
            float4 a0 = *(const float4*)(Wm + base);
            float4 a1 = *(const float4*)(Wm + base + 4);
            ushort4 o0, o1;
            o0.x = f2b(a0.x); o0.y = f2b(a0.y); o0.z = f2b(a0.z); o0.w = f2b(a0.w);
            o1.x = f2b(a1.x); o1.y = f2b(a1.y); o1.z = f2b(a1.z); o1.w = f2b(a1.w);
            *(ushort4*)(Am + base) = o0;
            *(ushort4*)(Am + base + 4) = o1;
        } else {
            // ---- BmT: BmT[hop][nn][j] = bf16(Wu2[hop][j][nn]) ----
            int tb = bb - 517;
            int hop = tb >> 6;
            int rem = tb & 63;
            int j0 = (rem & 7) * 32, n0 = (rem >> 3) * 32;
            const float* srcp = Wu + (size_t)hop * 512 * 256 + (size_t)256 * 256;
            unsigned short* dstp = BmT + (size_t)hop * 256 * 256;
            int tr = t >> 5, tc = t & 31;
#pragma unroll
            for (int r = 0; r < 4; ++r) {
                int j = tr + r * 8;
                T[tc][j] = srcp[(size_t)(j0 + j) * 256 + n0 + tc];
            }
            __syncthreads();
#pragma unroll
            for (int r = 0; r < 4; ++r) {
                int nn = tr + r * 8;
                dstp[(size_t)(n0 + nn) * 256 + j0 + tc] = f2b(T[nn][tc]);
            }
        }
    } else {
        // ---- init_h, NPB nodes per block ----
        int v0 = (b - histB - 773) * NPB;
        {
            int j = t >> 5, f = t & 31;
            int v = v0 + j;
            sb[t] = (v < n) ? nodes[(size_t)v * FDIM + f] : 0.f;
        }
        __syncthreads();
        float acc[NPB];
#pragma unroll
        for (int j = 0; j < NPB; ++j) {
            int v = v0 + j;
            acc[j] = (v < n) ? (b_proj[t] + type_emb[(size_t)node_types[v] * NDIM + t]) : 0.f;
        }
#pragma unroll 4
        for (int k = 0; k < FDIM; ++k) {
            float wv = W_proj[(size_t)k * NDIM + t];
#pragma unroll
            for (int j = 0; j < NPB; ++j)
                acc[j] += sb[j * FDIM + k] * wv;
        }
#pragma unroll
        for (int j = 0; j < NPB; ++j) {
            int v = v0 + j;
            if (v < n) {
                h[(size_t)v * NDIM + t] = f2b(acc[j]);
                h8[(size_t)v * NDIM + t] = f2fp8(acc[j]);
            }
        }
    }
}

// ---------- scan phase 1 (blocks 0..nch-1) + mm via MFMA (blocks nch..nch+7) ----------
__global__ __launch_bounds__(1024) void scan1_mm_kernel(
        const int* __restrict__ deg, int* __restrict__ rowptr,
        int* __restrict__ bsum, int nch, int n,
        const unsigned short* __restrict__ Am, const unsigned short* __restrict__ BmT,
        unsigned short* __restrict__ WtA, unsigned short* __restrict__ WtC) {
    int t = threadIdx.x;
    int b = blockIdx.x;
    if (b < nch) {
        __shared__ int wsum[16];
        int i = b * 1024 + t;
        int v = 0;
        if (i < n) v = (deg[i] + 7) & ~7;
        int lane = t & 63, wid = t >> 6;
        int x = v;
#pragma unroll
        for (int d = 1; d < 64; d <<= 1) {
            int u = __shfl_up(x, d, 64);
            if (lane >= d) x += u;
        }
        if (lane == 63) wsum[wid] = x;
        __syncthreads();
        if (wid == 0) {
            int ws = (lane < 16) ? wsum[lane] : 0;
#pragma unroll
            for (int d = 1; d < 16; d <<= 1) {
                int u = __shfl_up(ws, d, 64);
                if (lane >= d) ws += u;
            }
            if (lane < 16) wsum[lane] = ws;
        }
        __syncthreads();
        int excl = (wid > 0 ? wsum[wid - 1] : 0) + x - v;
        if (i < n) rowptr[i] = excl;
        if (t == 1023) bsum[b] = wsum[15];
        return;
    }

    // ---- MFMA mm, all-bf16 operands ----
    int m = b - nch;
    int hop = m >> 1, which = m & 1;
    const unsigned short* A = Am + (size_t)m * 65536;
    const unsigned short* B = BmT + (size_t)hop * 65536;
    unsigned short* W = (which ? WtC : WtA) + (size_t)hop * 65536;
    int wave = t >> 6, lane = t & 63;
    int l16 = lane & 15, quad = lane >> 4;
    int k0 = (wave & 3) * 64;
    int n0 = (wave >> 2) * 64;
    f32x4 acc[4][4];
#pragma unroll
    for (int i = 0; i < 4; ++i)
#pragma unroll
        for (int j = 0; j < 4; ++j) acc[i][j] = (f32x4)(0.f);

    for (int j0 = 0; j0 < 256; j0 += 32) {
        short8 af[4], bfr[4];
#pragma unroll
        for (int kt = 0; kt < 4; ++kt)
            af[kt] = *(const short8*)(A + (size_t)(k0 + kt * 16 + l16) * 256 + j0 + quad * 8);
#pragma unroll
        for (int nt = 0; nt < 4; ++nt)
            bfr[nt] = *(const short8*)(B + (size_t)(n0 + nt * 16 + l16) * 256 + j0 + quad * 8);
#pragma unroll
        for (int kt = 0; kt < 4; ++kt)
#pragma unroll
            for (int nt = 0; nt < 4; ++nt)
                acc[kt][nt] = __builtin_amdgcn_mfma_f32_16x16x32_bf16(af[kt], bfr[nt], acc[kt][nt], 0, 0, 0);
    }
#pragma unroll
    for (int kt = 0; kt < 4; ++kt)
#pragma unroll
        for (int nt = 0; nt < 4; ++nt) {
            int k = k0 + kt * 16 + quad * 4;
            int nn = n0 + nt * 16 + l16;
            ushort4 o;
            o.x = f2b(acc[kt][nt][0]); o.y = f2b(acc[kt][nt][1]);
            o.z = f2b(acc[kt][nt][2]); o.w = f2b(acc[kt][nt][3]);
            *(ushort4*)&W[(size_t)nn * 256 + k] = o;
        }
}

// ---------- scan phase 2 ----------
__global__ __launch_bounds__(1024) void scan2_kernel(
        int* __restrict__ rowptr, int* __restrict__ cursor,
        const int* __restrict__ bsum, int nch, int n) {
    __shared__ int soff, stot;
    int t = threadIdx.x;
    int b = blockIdx.x;
    if (t < 64) {
        int s = (t < nch) ? bsum[t] : 0;
        int x = s;
#pragma unroll
        for (int d = 1; d < 64; d <<= 1) {
            int u = __shfl_up(x, d, 64);
            if (t >= d) x += u;
        }
        if (t == 63) stot = x;
        if (t == b) soff = x - s;
    }
    __syncthreads();
    int i = b * 1024 + t;
    if (i < n) {
        int r = rowptr[i] + soff;
        rowptr[i] = r;
        cursor[i] = r;
    }
    if (b == 0 && t == 0) rowptr[n] = stot;
}

// ---------- fill + pad ----------
__global__ void fillpad_kernel(const int* __restrict__ src, const int* __restrict__ dst,
                               int* __restrict__ cursor,
                               const int* __restrict__ rowptr, const int* __restrict__ deg,
                               int* __restrict__ col, int E, int fillB, int n) {
    int b = blockIdx.x;
    int t = threadIdx.x;
    if (b < fillB) {
        int e = b * 256 + t;
        if (e < E) {
            int d = dst[e];
            int p = atomicAdd(&cursor[d], 1);
            col[p] = src[e];
        }
    } else {
        int v = (b - fillB) * 256 + t;
        if (v < n) {
            int s = rowptr[v] + deg[v];
            int e0 = rowptr[v + 1];
            for (int i = s; i < e0; ++i) col[i] = n;
        }
    }
}

// ---------- neighbor sum: 16-deep MLP main + 8-deep tail, int4 col-index loads ----------
// col+i is 32B-aligned (degrees padded to 8, prefix sums of multiples of 8), so the 16
// scalar col loads per chunk become 4 int4 loads (12 fewer VMEM instr in the hot loop).
// Accumulation order unchanged -> bit-exact.
__global__ __launch_bounds__(256) void agg_kernel(const unsigned char* __restrict__ h8,
                                                  const int* __restrict__ rowptr,
                                                  const int* __restrict__ col,
                                                  unsigned short* __restrict__ S, int n) {
    int wave = threadIdx.x >> 6;
    int lane = threadIdx.x & 63;
    int half = lane >> 5;
    int hl = lane & 31;
    int v = blockIdx.x * 8 + wave * 2 + half;
    if (v >= n) return;
    int beg = rowptr[v], end = rowptr[v + 1];
    float a[8];
#pragma unroll
    for (int e = 0; e < 8; ++e) a[e] = 0.f;
    int cofs = hl * 8;
    int i = beg;
    for (; i + 16 <= end; i += 16) {
        int4 c4[4];
        c4[0] = *(const int4*)(col + i);
        c4[1] = *(const int4*)(col + i + 4);
        c4[2] = *(const int4*)(col + i + 8);
        c4[3] = *(const int4*)(col + i + 12);
        const int* cc = (const int*)c4;
        uint2 x[16];
#pragma unroll
        for (int j = 0; j < 16; ++j)
            x[j] = *(const uint2*)(h8 + (size_t)cc[j] * NDIM + cofs);
#pragma unroll
        for (int j = 0; j < 16; ++j) {
            f32x2 p0 = __builtin_amdgcn_cvt_pk_f32_fp8(x[j].x, false);
            f32x2 p1 = __builtin_amdgcn_cvt_pk_f32_fp8(x[j].x, true);
            f32x2 p2 = __builtin_amdgcn_cvt_pk_f32_fp8(x[j].y, false);
            f32x2 p3 = __builtin_amdgcn_cvt_pk_f32_fp8(x[j].y, true);
            a[0] += p0[0]; a[1] += p0[1]; a[2] += p1[0]; a[3] += p1[1];
            a[4] += p2[0]; a[5] += p2[1]; a[6] += p3[0]; a[7] += p3[1];
        }
    }
    for (; i < end; i += 8) {
        int4 c4[2];
        c4[0] = *(const int4*)(col + i);
        c4[1] = *(const int4*)(col + i + 4);
        const int* cc = (const int*)c4;
        uint2 x[8];
#pragma unroll
        for (int j = 0; j < 8; ++j)
            x[j] = *(const uint2*)(h8 + (size_t)cc[j] * NDIM + cofs);
#pragma unroll
        for (int j = 0; j < 8; ++j) {
            f32x2 p0 = __builtin_amdgcn_cvt_pk_f32_fp8(x[j].x, false);
            f32x2 p1 = __builtin_amdgcn_cvt_pk_f32_fp8(x[j].x, true);
            f32x2 p2 = __builtin_amdgcn_cvt_pk_f32_fp8(x[j].y, false);
            f32x2 p3 = __builtin_amdgcn_cvt_pk_f32_fp8(x[j].y, true);
            a[0] += p0[0]; a[1] += p0[1]; a[2] += p1[0]; a[3] += p1[1];
            a[4] += p2[0]; a[5] += p2[1]; a[6] += p3[0]; a[7] += p3[1];
        }
    }
    uint4 o;
    unsigned short* op = (unsigned short*)&o;
#pragma unroll
    for (int e = 0; e < 8; ++e) op[e] = f2b(a[e]);
    *(uint4*)&S[(size_t)v * NDIM + cofs] = o;
}

// ---------- fused hop GEMM: BM=128 BN=64 BK=64, gload_lds + XOR swizzle, 4 blocks/CU ----------
#define BM 128
#define BN 64
#define BK 64

template <bool LAST>
__global__ __launch_bounds__(256, 4) void gemm_hop_kernel(const unsigned short* __restrict__ S,
                                                          const unsigned short* __restrict__ hcur,
                                                          const int* __restrict__ deg,
                                                          const unsigned short* __restrict__ WtA,
                                                          const unsigned short* __restrict__ WtB,
                                                          const unsigned short* __restrict__ WtC,
                                                          const float* __restrict__ bupd,
                                                          const float* __restrict__ cvec,
                                                          unsigned short* __restrict__ Out,
                                                          unsigned char* __restrict__ Out8,
                                                          int* __restrict__ geInt, int n) {
    __shared__ unsigned short As[BM * BK];   // 16KB
    __shared__ unsigned short Bs[BN * BK];   // 8KB
    __shared__ unsigned short Cs[BN * BK];   // 8KB
    __shared__ int smax[BN];
    int t = threadIdx.x;
    int lane = t & 63;
    int w = t >> 6;
    int wm = w >> 1, wn = w & 1;
    int quad = lane >> 4, l16 = lane & 15;
    int row0 = blockIdx.x * BM;
    int n0 = blockIdx.y * BN;

    if (LAST) {
        if (t < BN) smax[t] = 0;
    }

    f32x4 acc1[4][2], acc2[4][2];
#pragma unroll
    for (int i = 0; i < 4; ++i)
#pragma unroll
        for (int j = 0; j < 2; ++j) { acc1[i][j] = (f32x4)(0.f); acc2[i][j] = (f32x4)(0.f); }

    // phase 1: acc1 += S @ M1^T
    for (int k0 = 0; k0 < NDIM; k0 += BK) {
        __syncthreads();
#pragma unroll
        for (int h2 = 0; h2 < 4; ++h2) {
            int c = t + h2 * 256;
            int r = c >> 3;
            int cb = (c & 7) ^ (r & 7);          // pre-swizzled logical block
            int grow = row0 + r; if (grow >= n) grow = n - 1;
            __builtin_amdgcn_global_load_lds(
                (const unsigned int*)(S + (size_t)grow * NDIM + k0 + cb * 8),
                (unsigned int*)(As + (size_t)(h2 * 256 + w * 64) * 8), 16, 0, 0);
        }
#pragma unroll
        for (int h2 = 0; h2 < 2; ++h2) {
            int c = t + h2 * 256;
            int r = c >> 3;
            int cb = (c & 7) ^ (r & 7);
            __builtin_amdgcn_global_load_lds(
                (const unsigned int*)(WtA + (size_t)(n0 + r) * NDIM + k0 + cb * 8),
                (unsigned int*)(Bs + (size_t)(h2 * 256 + w * 64) * 8), 16, 0, 0);
        }
        __syncthreads();
#pragma unroll
        for (int ks = 0; ks < BK; ks += 32) {
            short8 af[4], bf[2];
#pragma unroll
            for (int mt = 0; mt < 4; ++mt) {
                int ar = wm * 64 + mt * 16 + l16;
                int acb = ((ks >> 3) + quad) ^ (ar & 7);
                af[mt] = *(const short8*)&As[ar * BK + acb * 8];
            }
#pragma unroll
            for (int nt = 0; nt < 2; ++nt) {
                int br = wn * 32 + nt * 16 + l16;
                int bcb = ((ks >> 3) + quad) ^ (br & 7);
                bf[nt] = *(const short8*)&Bs[br * BK + bcb * 8];
            }
#pragma unroll
            for (int mt = 0; mt < 4; ++mt)
#pragma unroll
                for (int nt = 0; nt < 2; ++nt)
                    acc1[mt][nt] = __builtin_amdgcn_mfma_f32_16x16x32_bf16(af[mt], bf[nt], acc1[mt][nt], 0, 0, 0);
        }
    }
    // phase 2: acc1 += h @ Wu1^T ; acc2 += h @ M2^T
    for (int k0 = 0; k0 < NDIM; k0 += BK) {
        __syncthreads();
#pragma unroll
        for (int h2 = 0; h2 < 4; ++h2) {
            int c = t + h2 * 256;
            int r = c >> 3;
            int cb = (c & 7) ^ (r & 7);
            int grow = row0 + r; if (grow >= n) grow = n - 1;
            __builtin_amdgcn_global_load_lds(
                (const unsigned int*)(hcur + (size_t)grow * NDIM + k0 + cb * 8),
                (unsigned int*)(As + (size_t)(h2 * 256 + w * 64) * 8), 16, 0, 0);
        }
#pragma unroll
        for (int h2 = 0; h2 < 2; ++h2) {
            int c = t + h2 * 256;
            int r = c >> 3;
            int cb = (c & 7) ^ (r & 7);
            size_t widx = (size_t)(n0 + r) * NDIM + k0 + cb * 8;
            __builtin_amdgcn_global_load_lds(
                (const unsigned int*)(WtB + widx),
                (unsigned int*)(Bs + (size_t)(h2 * 256 + w * 64) * 8), 16, 0, 0);
            __builtin_amdgcn_global_load_lds(
                (const unsigned int*)(WtC + widx),
                (unsigned int*)(Cs + (size_t)(h2 * 256 + w * 64) * 8), 16, 0, 0);
        }
        __syncthreads();
#pragma unroll
        for (int ks = 0; ks < BK; ks += 32) {
            short8 af[4], bf[2], cf[2];
#pragma unroll
            for (int mt = 0; mt < 4; ++mt) {
                int ar = wm * 64 + mt * 16 + l16;
                int acb = ((ks >> 3) + quad) ^ (ar & 7);
                af[mt] = *(const short8*)&As[ar * BK + acb * 8];
            }
#pragma unroll
            for (int nt = 0; nt < 2; ++nt) {
                int br = wn * 32 + nt * 16 + l16;
                int bcb = ((ks >> 3) + quad) ^ (br & 7);
                bf[nt] = *(const short8*)&Bs[br * BK + bcb * 8];
                cf[nt] = *(const short8*)&Cs[br * BK + bcb * 8];
            }
#pragma unroll
            for (int mt = 0; mt < 4; ++mt)
#pragma unroll
                for (int nt = 0; nt < 2; ++nt) {
                    acc1[mt][nt] = __builtin_amdgcn_mfma_f32_16x16x32_bf16(af[mt], bf[nt], acc1[mt][nt], 0, 0, 0);
                    acc2[mt][nt] = __builtin_amdgcn_mfma_f32_16x16x32_bf16(af[mt], cf[nt], acc2[mt][nt], 0, 0, 0);
                }
        }
    }
    // epilogue
#pragma unroll
    for (int mt = 0; mt < 4; ++mt) {
#pragma unroll
        for (int nt = 0; nt < 2; ++nt) {
            int lcol = wn * 32 + nt * 16 + l16;
            int col = n0 + lcol;
            float bu = bupd[col];
            float cv = cvec[col];
            float cmax = 0.f;
#pragma unroll
            for (int r = 0; r < 4; ++r) {
                int row = row0 + wm * 64 + mt * 16 + quad * 4 + r;
                if (row < n) {
                    float dg = (float)deg[row];
                    float v = fmaxf(acc1[mt][nt][r] + dg * (acc2[mt][nt][r] + cv) + bu, 0.f);
                    Out[(size_t)row * NDIM + col] = f2b(v);
                    if (!LAST) Out8[(size_t)row * NDIM + col] = f2fp8(v);
                    if (LAST) cmax = fmaxf(cmax, v);
                }
            }
            if (LAST) atomicMax(&smax[lcol], __float_as_int(cmax));
        }
    }
    if (LAST) {
        __syncthreads();
        if (t < BN) atomicMax(&geInt[n0 + t], smax[t]);
    }
}

// ---------- final ----------
__global__ __launch_bounds__(1024) void out_kernel(const float* __restrict__ ge,
                                                   const float* __restrict__ W_out,
                                                   const float* __restrict__ b_out,
                                                   float* __restrict__ out) {
    __shared__ float red[4][NDIM];
    int t = threadIdx.x & 255;
    int g = threadIdx.x >> 8;
    float acc = 0.f;
#pragma unroll 8
    for (int kk = 0; kk < 64; ++kk) {
        int k = g * 64 + kk;
        acc += ge[k] * W_out[k * NDIM + t];
    }
    red[g][t] = acc;
    __syncthreads();
    if (g == 0)
        out[t] = b_out[t] + red[0][t] + red[1][t] + red[2][t] + red[3][t];
}

// ---------- launch ----------
extern "C" void kernel_launch(void* const* d_in, const int* in_sizes, int n_in,
                              void* d_out, int out_size, void* d_ws, size_t ws_size,
                              hipStream_t stream) {
    const float* nodes      = (const float*)d_in[0];
    const int*   edges      = (const int*)d_in[1];
    const int*   node_types = (const int*)d_in[2];
    const float* type_emb   = (const float*)d_in[3];
    const float* W_proj     = (const float*)d_in[4];
    const float* b_proj     = (const float*)d_in[5];
    const float* W_msg      = (const float*)d_in[6];
    const float* b_msg      = (const float*)d_in[7];
    const float* W_upd      = (const float*)d_in[8];
    const float* b_upd      = (const float*)d_in[9];
    const float* W_out      = (const float*)d_in[10];
    const float* b_out      = (const float*)d_in[11];

    int n = in_sizes[2];
    int E = in_sizes[1] / 2;
    const int* src = edges;
    const int* dst = edges + E;

    size_t off = 0;
    auto alloc = [&](size_t bytes) {
        void* p = (char*)d_ws + off;
        off += (bytes + 255) & ~(size_t)255;
        return p;
    };
    int* deg    = (int*)alloc((size_t)(n + 4096) * 4);
    int* rowptr = (int*)alloc((size_t)(n + 1) * 4);
    int* cursor = (int*)alloc((size_t)n * 4);
    int* bsum   = (int*)alloc((size_t)256 * 4);
    int* col    = (int*)alloc((size_t)(E + 8 * n) * 4);
    unsigned short* WtA = (unsigned short*)alloc((size_t)HOPS * 256 * 256 * 2);
    unsigned short* WtB = (unsigned short*)alloc((size_t)HOPS * 256 * 256 * 2);
    unsigned short* WtC = (unsigned short*)alloc((size_t)HOPS * 256 * 256 * 2);
    unsigned short* Am  = (unsigned short*)alloc((size_t)8 * 256 * 256 * 2);
    unsigned short* BmT = (unsigned short*)alloc((size_t)HOPS * 256 * 256 * 2);
    float* cvec = (float*)alloc((size_t)HOPS * 256 * 4);
    int* geInt  = (int*)alloc((size_t)256 * 4);
    unsigned short* hA  = (unsigned short*)alloc((size_t)(n + 1) * NDIM * 2);
    unsigned short* hB  = (unsigned short*)alloc((size_t)(n + 1) * NDIM * 2);
    unsigned short* Sb  = (unsigned short*)alloc((size_t)n * NDIM * 2);
    unsigned char* h8   = (unsigned char*)alloc((size_t)(n + 1) * NDIM);

    hipMemsetAsync(deg, 0, (size_t)(n + 4096) * 4, stream);
    int hb = (E + 1023) / 1024;    // hist blocks: 4 edges/thread
    int eb = (E + 255) / 256;      // fill blocks (unchanged)
    int pb = (n + 255) / 256;
    int ib = (n + NPB - 1) / NPB;
    int nch = (n + 1023) / 1024;
    prep_mega_kernel<<<hb + 773 + ib, 256, 0, stream>>>(
        dst, deg, E, hb,
        W_msg, W_upd, b_msg, WtB, Am, BmT, cvec, geInt, h8 + (size_t)n * NDIM,
        nodes, node_types, type_emb, W_proj, b_proj, hA, h8, n);
    scan1_mm_kernel<<<nch + 8, 1024, 0, stream>>>(deg, rowptr, bsum, nch, n, Am, BmT, WtA, WtC);
    scan2_kernel<<<nch, 1024, 0, stream>>>(rowptr, cursor, bsum, nch, n);
    fillpad_kernel<<<eb + pb, 256, 0, stream>>>(src, dst, cursor, rowptr, deg, col, E, eb, n);

    unsigned short* h  = hA;
    unsigned short* ho = hB;
    int gx = (n + BM - 1) / BM;
    dim3 ggrid(gx, NDIM / BN);
    for (int i = 0; i < HOPS; ++i) {
        agg_kernel<<<(n + 7) / 8, 256, 0, stream>>>(h8, rowptr, col, Sb, n);
        size_t wofs = (size_t)i * 256 * 256;
        if (i == HOPS - 1)
            gemm_hop_kernel<true><<<ggrid, 256, 0, stream>>>(
                Sb, h, deg, WtA + wofs, WtB + wofs, WtC + wofs,
                b_upd + (size_t)i * NDIM, cvec + (size_t)i * NDIM, ho, h8, geInt, n);
        else
            gemm_hop_kernel<false><<<ggrid, 256, 0, stream>>>(
                Sb, h, deg, WtA + wofs, WtB + wofs, WtC + wofs,
                b_upd + (size_t)i * NDIM, cvec + (size_t)i * NDIM, ho, h8, geInt, n);
        unsigned short* tmp = h; h = ho; ho = tmp;
    }
    out_kernel<<<1, 1024, 0, stream>>>((const float*)geInt, W_out, b_out, (float*)d_out);
}

// Round 9
// 328.500 us; speedup vs baseline: 1.1997x; 1.0112x over previous
//
#include <hip/hip_runtime.h>
#include <hip/hip_bf16.h>

#define NDIM 256
#define FDIM 32
#define HOPS 4
#define NPB 16  // nodes per init block

typedef __attribute__((ext_vector_type(8))) short short8;
typedef __attribute__((ext_vector_type(4))) float f32x4;
typedef __attribute__((ext_vector_type(2))) float f32x2;

// ---------- helpers ----------
__device__ inline float b2f(unsigned short u) {
    union { unsigned int i; float f; } v; v.i = ((unsigned int)u) << 16; return v.f;
}
__device__ inline unsigned short f2b(float f) {
    union { float f; unsigned int i; } v; v.f = f;
    unsigned int r = v.i + 0x7FFF + ((v.i >> 16) & 1);
    return (unsigned short)(r >> 16);
}
__device__ inline unsigned char f2fp8(float v) {
    return (unsigned char)(__builtin_amdgcn_cvt_pk_fp8_f32(v, v, 0, false) & 0xFF);
}

// ---------- prep mega ----------
// init_h now does NPB=16 nodes/block (halves block count + W_proj re-reads; VGPR stays <=64).
__global__ __launch_bounds__(256) void prep_mega_kernel(
        const int* __restrict__ dst, int* __restrict__ deg, int E, int histB,
        const float* __restrict__ Wm, const float* __restrict__ Wu,
        const float* __restrict__ bm,
        unsigned short* __restrict__ WtB,
        unsigned short* __restrict__ Am, unsigned short* __restrict__ BmT,
        float* __restrict__ cvec, int* __restrict__ geInt,
        unsigned char* __restrict__ h8row,
        const float* __restrict__ nodes, const int* __restrict__ node_types,
        const float* __restrict__ type_emb, const float* __restrict__ W_proj,
        const float* __restrict__ b_proj,
        unsigned short* __restrict__ h, unsigned char* __restrict__ h8, int n) {
    __shared__ float T[32][33];
    __shared__ float sb[512];
    int b = blockIdx.x;
    int t = threadIdx.x;

    if (b < histB) {
        int e = (b * 256 + t) * 4;
        if (e + 3 < E) {
            int4 d = *(const int4*)(dst + e);
            atomicAdd(&deg[d.x], 1);
            atomicAdd(&deg[d.y], 1);
            atomicAdd(&deg[d.z], 1);
            atomicAdd(&deg[d.w], 1);
        } else {
            for (int k = e; k < E; ++k) atomicAdd(&deg[dst[k]], 1);
        }
    } else if (b < histB + 773) {
        int bb = b - histB;
        if (bb < 256) {
            // ---- wtrans: WtB[hop][nn][k] = W_upd[hop][k][nn] ----
            int hop = bb >> 6;
            int rem = bb & 63;
            int k0 = (rem & 7) * 32, n0 = (rem >> 3) * 32;
            const float* src = Wu + (size_t)hop * 512 * 256;
            unsigned short* dstp = WtB + (size_t)hop * 256 * 256;
            int tr = t >> 5, tc = t & 31;
#pragma unroll
            for (int r = 0; r < 4; ++r) {
                int k = tr + r * 8;
                T[tc][k] = src[(size_t)(k0 + k) * 256 + n0 + tc];
            }
            __syncthreads();
#pragma unroll
            for (int r = 0; r < 4; ++r) {
                int nn = tr + r * 8;
                dstp[(size_t)(n0 + nn) * 256 + k0 + tc] = f2b(T[nn][tc]);
            }
        } else if (bb < 260) {
            int hop = bb - 256;
            sb[t] = bm[hop * 256 + t];
            __syncthreads();
            const float* B = Wu + (size_t)hop * 512 * 256 + (size_t)256 * 256;
            float acc = 0.f;
#pragma unroll 8
            for (int j = 0; j < 256; ++j) acc += sb[j] * B[(size_t)j * 256 + t];
            cvec[hop * 256 + t] = acc;
        } else if (bb == 260) {
            geInt[t] = 0;
            h8row[t] = 0;
        } else if (bb < 517) {
            // ---- Am: flat fp32->bf16 of W_msg ----
            size_t base = (size_t)(bb - 261) * 2048 + (size_t)t * 8;
            float4 a0 = *(const float4*)(Wm + base);
            float4 a1 = *(const float4*)(Wm + base + 4);
            ushort4 o0, o1;
            o0.x = f2b(a0.x); o0.y = f2b(a0.y); o0.z = f2b(a0.z); o0.w = f2b(a0.w);
            o1.x = f2b(a1.x); o1.y = f2b(a1.y); o1.z = f2b(a1.z); o1.w = f2b(a1.w);
            *(ushort4*)(Am + base) = o0;
            *(ushort4*)(Am + base + 4) = o1;
        } else {
            // ---- BmT: BmT[hop][nn][j] = bf16(Wu2[hop][j][nn]) ----
            int tb = bb - 517;
            int hop = tb >> 6;
            int rem = tb & 63;
            int j0 = (rem & 7) * 32, n0 = (rem >> 3) * 32;
            const float* srcp = Wu + (size_t)hop * 512 * 256 + (size_t)256 * 256;
            unsigned short* dstp = BmT + (size_t)hop * 256 * 256;
            int tr = t >> 5, tc = t & 31;
#pragma unroll
            for (int r = 0; r < 4; ++r) {
                int j = tr + r * 8;
                T[tc][j] = srcp[(size_t)(j0 + j) * 256 + n0 + tc];
            }
            __syncthreads();
#pragma unroll
            for (int r = 0; r < 4; ++r) {
                int nn = tr + r * 8;
                dstp[(size_t)(n0 + nn) * 256 + j0 + tc] = f2b(T[nn][tc]);
            }
        }
    } else {
        // ---- init_h, NPB=16 nodes per block ----
        int v0 = (b - histB - 773) * NPB;
#pragma unroll
        for (int s = 0; s < 2; ++s) {
            int idx = t + s * 256;
            int j = idx >> 5, f = idx & 31;
            int v = v0 + j;
            sb[idx] = (v < n) ? nodes[(size_t)v * FDIM + f] : 0.f;
        }
        __syncthreads();
        float acc[NPB];
#pragma unroll
        for (int j = 0; j < NPB; ++j) {
            int v = v0 + j;
            acc[j] = (v < n) ? (b_proj[t] + type_emb[(size_t)node_types[v] * NDIM + t]) : 0.f;
        }
#pragma unroll 4
        for (int k = 0; k < FDIM; ++k) {
            float wv = W_proj[(size_t)k * NDIM + t];
#pragma unroll
            for (int j = 0; j < NPB; ++j)
                acc[j] += sb[j * FDIM + k] * wv;
        }
#pragma unroll
        for (int j = 0; j < NPB; ++j) {
            int v = v0 + j;
            if (v < n) {
                h[(size_t)v * NDIM + t] = f2b(acc[j]);
                h8[(size_t)v * NDIM + t] = f2fp8(acc[j]);
            }
        }
    }
}

// ---------- scan phase 1 (blocks 0..nch-1) + mm via MFMA (blocks nch..nch+7) ----------
__global__ __launch_bounds__(1024) void scan1_mm_kernel(
        const int* __restrict__ deg, int* __restrict__ rowptr,
        int* __restrict__ bsum, int nch, int n,
        const unsigned short* __restrict__ Am, const unsigned short* __restrict__ BmT,
        unsigned short* __restrict__ WtA, unsigned short* __restrict__ WtC) {
    int t = threadIdx.x;
    int b = blockIdx.x;
    if (b < nch) {
        __shared__ int wsum[16];
        int i = b * 1024 + t;
        int v = 0;
        if (i < n) v = (deg[i] + 7) & ~7;
        int lane = t & 63, wid = t >> 6;
        int x = v;
#pragma unroll
        for (int d = 1; d < 64; d <<= 1) {
            int u = __shfl_up(x, d, 64);
            if (lane >= d) x += u;
        }
        if (lane == 63) wsum[wid] = x;
        __syncthreads();
        if (wid == 0) {
            int ws = (lane < 16) ? wsum[lane] : 0;
#pragma unroll
            for (int d = 1; d < 16; d <<= 1) {
                int u = __shfl_up(ws, d, 64);
                if (lane >= d) ws += u;
            }
            if (lane < 16) wsum[lane] = ws;
        }
        __syncthreads();
        int excl = (wid > 0 ? wsum[wid - 1] : 0) + x - v;
        if (i < n) rowptr[i] = excl;
        if (t == 1023) bsum[b] = wsum[15];
        return;
    }

    // ---- MFMA mm, all-bf16 operands ----
    int m = b - nch;
    int hop = m >> 1, which = m & 1;
    const unsigned short* A = Am + (size_t)m * 65536;
    const unsigned short* B = BmT + (size_t)hop * 65536;
    unsigned short* W = (which ? WtC : WtA) + (size_t)hop * 65536;
    int wave = t >> 6, lane = t & 63;
    int l16 = lane & 15, quad = lane >> 4;
    int k0 = (wave & 3) * 64;
    int n0 = (wave >> 2) * 64;
    f32x4 acc[4][4];
#pragma unroll
    for (int i = 0; i < 4; ++i)
#pragma unroll
        for (int j = 0; j < 4; ++j) acc[i][j] = (f32x4)(0.f);

    for (int j0 = 0; j0 < 256; j0 += 32) {
        short8 af[4], bfr[4];
#pragma unroll
        for (int kt = 0; kt < 4; ++kt)
            af[kt] = *(const short8*)(A + (size_t)(k0 + kt * 16 + l16) * 256 + j0 + quad * 8);
#pragma unroll
        for (int nt = 0; nt < 4; ++nt)
            bfr[nt] = *(const short8*)(B + (size_t)(n0 + nt * 16 + l16) * 256 + j0 + quad * 8);
#pragma unroll
        for (int kt = 0; kt < 4; ++kt)
#pragma unroll
            for (int nt = 0; nt < 4; ++nt)
                acc[kt][nt] = __builtin_amdgcn_mfma_f32_16x16x32_bf16(af[kt], bfr[nt], acc[kt][nt], 0, 0, 0);
    }
#pragma unroll
    for (int kt = 0; kt < 4; ++kt)
#pragma unroll
        for (int nt = 0; nt < 4; ++nt) {
            int k = k0 + kt * 16 + quad * 4;
            int nn = n0 + nt * 16 + l16;
            ushort4 o;
            o.x = f2b(acc[kt][nt][0]); o.y = f2b(acc[kt][nt][1]);
            o.z = f2b(acc[kt][nt][2]); o.w = f2b(acc[kt][nt][3]);
            *(ushort4*)&W[(size_t)nn * 256 + k] = o;
        }
}

// ---------- scan phase 2 ----------
__global__ __launch_bounds__(1024) void scan2_kernel(
        int* __restrict__ rowptr, int* __restrict__ cursor,
        const int* __restrict__ bsum, int nch, int n) {
    __shared__ int soff, stot;
    int t = threadIdx.x;
    int b = blockIdx.x;
    if (t < 64) {
        int s = (t < nch) ? bsum[t] : 0;
        int x = s;
#pragma unroll
        for (int d = 1; d < 64; d <<= 1) {
            int u = __shfl_up(x, d, 64);
            if (t >= d) x += u;
        }
        if (t == 63) stot = x;
        if (t == b) soff = x - s;
    }
    __syncthreads();
    int i = b * 1024 + t;
    if (i < n) {
        int r = rowptr[i] + soff;
        rowptr[i] = r;
        cursor[i] = r;
    }
    if (b == 0 && t == 0) rowptr[n] = stot;
}

// ---------- fill + pad ----------
__global__ void fillpad_kernel(const int* __restrict__ src, const int* __restrict__ dst,
                               int* __restrict__ cursor,
                               const int* __restrict__ rowptr, const int* __restrict__ deg,
                               int* __restrict__ col, int E, int fillB, int n) {
    int b = blockIdx.x;
    int t = threadIdx.x;
    if (b < fillB) {
        int e = b * 256 + t;
        if (e < E) {
            int d = dst[e];
            int p = atomicAdd(&cursor[d], 1);
            col[p] = src[e];
        }
    } else {
        int v = (b - fillB) * 256 + t;
        if (v < n) {
            int s = rowptr[v] + deg[v];
            int e0 = rowptr[v + 1];
            for (int i = s; i < e0; ++i) col[i] = n;
        }
    }
}

// ---------- neighbor sum: 16-deep MLP + software-pipelined col loads ----------
// vmcnt is FIFO: iter i+1's col load issued after iter i's gathers can't be awaited
// without draining the gathers. Prefetching next chunk's col indices before processing
// the current chunk hides col-load latency under gather issue. Order unchanged -> bit-exact.
__global__ __launch_bounds__(256) void agg_kernel(const unsigned char* __restrict__ h8,
                                                  const int* __restrict__ rowptr,
                                                  const int* __restrict__ col,
                                                  unsigned short* __restrict__ S, int n) {
    int wave = threadIdx.x >> 6;
    int lane = threadIdx.x & 63;
    int half = lane >> 5;
    int hl = lane & 31;
    int v = blockIdx.x * 8 + wave * 2 + half;
    if (v >= n) return;
    int beg = rowptr[v], end = rowptr[v + 1];
    float a[8];
#pragma unroll
    for (int e = 0; e < 8; ++e) a[e] = 0.f;
    int cofs = hl * 8;
    int i = beg;
    if (i + 16 <= end) {
        int4 cA0 = *(const int4*)(col + i);
        int4 cA1 = *(const int4*)(col + i + 4);
        int4 cA2 = *(const int4*)(col + i + 8);
        int4 cA3 = *(const int4*)(col + i + 12);
        for (; i + 32 <= end; i += 16) {
            int4 cB0 = *(const int4*)(col + i + 16);
            int4 cB1 = *(const int4*)(col + i + 20);
            int4 cB2 = *(const int4*)(col + i + 24);
            int4 cB3 = *(const int4*)(col + i + 28);
            int4 c4[4] = {cA0, cA1, cA2, cA3};
            const int* cc = (const int*)c4;
            uint2 x[16];
#pragma unroll
            for (int j = 0; j < 16; ++j)
                x[j] = *(const uint2*)(h8 + (size_t)cc[j] * NDIM + cofs);
#pragma unroll
            for (int j = 0; j < 16; ++j) {
                f32x2 p0 = __builtin_amdgcn_cvt_pk_f32_fp8(x[j].x, false);
                f32x2 p1 = __builtin_amdgcn_cvt_pk_f32_fp8(x[j].x, true);
                f32x2 p2 = __builtin_amdgcn_cvt_pk_f32_fp8(x[j].y, false);
                f32x2 p3 = __builtin_amdgcn_cvt_pk_f32_fp8(x[j].y, true);
                a[0] += p0[0]; a[1] += p0[1]; a[2] += p1[0]; a[3] += p1[1];
                a[4] += p2[0]; a[5] += p2[1]; a[6] += p3[0]; a[7] += p3[1];
            }
            cA0 = cB0; cA1 = cB1; cA2 = cB2; cA3 = cB3;
        }
        {
            int4 c4[4] = {cA0, cA1, cA2, cA3};
            const int* cc = (const int*)c4;
            uint2 x[16];
#pragma unroll
            for (int j = 0; j < 16; ++j)
                x[j] = *(const uint2*)(h8 + (size_t)cc[j] * NDIM + cofs);
#pragma unroll
            for (int j = 0; j < 16; ++j) {
                f32x2 p0 = __builtin_amdgcn_cvt_pk_f32_fp8(x[j].x, false);
                f32x2 p1 = __builtin_amdgcn_cvt_pk_f32_fp8(x[j].x, true);
                f32x2 p2 = __builtin_amdgcn_cvt_pk_f32_fp8(x[j].y, false);
                f32x2 p3 = __builtin_amdgcn_cvt_pk_f32_fp8(x[j].y, true);
                a[0] += p0[0]; a[1] += p0[1]; a[2] += p1[0]; a[3] += p1[1];
                a[4] += p2[0]; a[5] += p2[1]; a[6] += p3[0]; a[7] += p3[1];
            }
            i += 16;
        }
    }
    for (; i < end; i += 8) {
        int4 c4[2];
        c4[0] = *(const int4*)(col + i);
        c4[1] = *(const int4*)(col + i + 4);
        const int* cc = (const int*)c4;
        uint2 x[8];
#pragma unroll
        for (int j = 0; j < 8; ++j)
            x[j] = *(const uint2*)(h8 + (size_t)cc[j] * NDIM + cofs);
#pragma unroll
        for (int j = 0; j < 8; ++j) {
            f32x2 p0 = __builtin_amdgcn_cvt_pk_f32_fp8(x[j].x, false);
            f32x2 p1 = __builtin_amdgcn_cvt_pk_f32_fp8(x[j].x, true);
            f32x2 p2 = __builtin_amdgcn_cvt_pk_f32_fp8(x[j].y, false);
            f32x2 p3 = __builtin_amdgcn_cvt_pk_f32_fp8(x[j].y, true);
            a[0] += p0[0]; a[1] += p0[1]; a[2] += p1[0]; a[3] += p1[1];
            a[4] += p2[0]; a[5] += p2[1]; a[6] += p3[0]; a[7] += p3[1];
        }
    }
    uint4 o;
    unsigned short* op = (unsigned short*)&o;
#pragma unroll
    for (int e = 0; e < 8; ++e) op[e] = f2b(a[e]);
    *(uint4*)&S[(size_t)v * NDIM + cofs] = o;
}

// ---------- fused hop GEMM: BM=128 BN=64 BK=64, gload_lds + XOR swizzle, 4 blocks/CU ----------
// 1D grid with XCD-grouped decode: the 4 column-blocks (by=0..3) sharing the same A-panel
// rows get bids with equal bid%8 (same XCD under round-robin dispatch) and adjacent
// per-XCD slots -> A-panel fetched once from L3 then served from that XCD's L2.
// Bijective with early-exit padding blocks.
#define BM 128
#define BN 64
#define BK 64

template <bool LAST>
__global__ __launch_bounds__(256, 4) void gemm_hop_kernel(const unsigned short* __restrict__ S,
                                                          const unsigned short* __restrict__ hcur,
                                                          const int* __restrict__ deg,
                                                          const unsigned short* __restrict__ WtA,
                                                          const unsigned short* __restrict__ WtB,
                                                          const unsigned short* __restrict__ WtC,
                                                          const float* __restrict__ bupd,
                                                          const float* __restrict__ cvec,
                                                          unsigned short* __restrict__ Out,
                                                          unsigned char* __restrict__ Out8,
                                                          int* __restrict__ geInt, int n) {
    __shared__ unsigned short As[BM * BK];   // 16KB
    __shared__ unsigned short Bs[BN * BK];   // 8KB
    __shared__ unsigned short Cs[BN * BK];   // 8KB
    __shared__ int smax[BN];

    int gx = (n + BM - 1) / BM;
    int bid = blockIdx.x;
    int xcd = bid & 7;
    int q = bid >> 3;
    int g = (q >> 2) * 8 + xcd;     // row-group (bx)
    int by = q & 3;
    if (g >= gx) return;
    int row0 = g * BM;
    int n0 = by * BN;

    int t = threadIdx.x;
    int lane = t & 63;
    int w = t >> 6;
    int wm = w >> 1, wn = w & 1;
    int quad = lane >> 4, l16 = lane & 15;

    if (LAST) {
        if (t < BN) smax[t] = 0;
    }

    f32x4 acc1[4][2], acc2[4][2];
#pragma unroll
    for (int i = 0; i < 4; ++i)
#pragma unroll
        for (int j = 0; j < 2; ++j) { acc1[i][j] = (f32x4)(0.f); acc2[i][j] = (f32x4)(0.f); }

    // phase 1: acc1 += S @ M1^T
    for (int k0 = 0; k0 < NDIM; k0 += BK) {
        __syncthreads();
#pragma unroll
        for (int h2 = 0; h2 < 4; ++h2) {
            int c = t + h2 * 256;
            int r = c >> 3;
            int cb = (c & 7) ^ (r & 7);          // pre-swizzled logical block
            int grow = row0 + r; if (grow >= n) grow = n - 1;
            __builtin_amdgcn_global_load_lds(
                (const unsigned int*)(S + (size_t)grow * NDIM + k0 + cb * 8),
                (unsigned int*)(As + (size_t)(h2 * 256 + w * 64) * 8), 16, 0, 0);
        }
#pragma unroll
        for (int h2 = 0; h2 < 2; ++h2) {
            int c = t + h2 * 256;
            int r = c >> 3;
            int cb = (c & 7) ^ (r & 7);
            __builtin_amdgcn_global_load_lds(
                (const unsigned int*)(WtA + (size_t)(n0 + r) * NDIM + k0 + cb * 8),
                (unsigned int*)(Bs + (size_t)(h2 * 256 + w * 64) * 8), 16, 0, 0);
        }
        __syncthreads();
#pragma unroll
        for (int ks = 0; ks < BK; ks += 32) {
            short8 af[4], bf[2];
#pragma unroll
            for (int mt = 0; mt < 4; ++mt) {
                int ar = wm * 64 + mt * 16 + l16;
                int acb = ((ks >> 3) + quad) ^ (ar & 7);
                af[mt] = *(const short8*)&As[ar * BK + acb * 8];
            }
#pragma unroll
            for (int nt = 0; nt < 2; ++nt) {
                int br = wn * 32 + nt * 16 + l16;
                int bcb = ((ks >> 3) + quad) ^ (br & 7);
                bf[nt] = *(const short8*)&Bs[br * BK + bcb * 8];
            }
#pragma unroll
            for (int mt = 0; mt < 4; ++mt)
#pragma unroll
                for (int nt = 0; nt < 2; ++nt)
                    acc1[mt][nt] = __builtin_amdgcn_mfma_f32_16x16x32_bf16(af[mt], bf[nt], acc1[mt][nt], 0, 0, 0);
        }
    }
    // phase 2: acc1 += h @ Wu1^T ; acc2 += h @ M2^T
    for (int k0 = 0; k0 < NDIM; k0 += BK) {
        __syncthreads();
#pragma unroll
        for (int h2 = 0; h2 < 4; ++h2) {
            int c = t + h2 * 256;
            int r = c >> 3;
            int cb = (c & 7) ^ (r & 7);
            int grow = row0 + r; if (grow >= n) grow = n - 1;
            __builtin_amdgcn_global_load_lds(
                (const unsigned int*)(hcur + (size_t)grow * NDIM + k0 + cb * 8),
                (unsigned int*)(As + (size_t)(h2 * 256 + w * 64) * 8), 16, 0, 0);
        }
#pragma unroll
        for (int h2 = 0; h2 < 2; ++h2) {
            int c = t + h2 * 256;
            int r = c >> 3;
            int cb = (c & 7) ^ (r & 7);
            size_t widx = (size_t)(n0 + r) * NDIM + k0 + cb * 8;
            __builtin_amdgcn_global_load_lds(
                (const unsigned int*)(WtB + widx),
                (unsigned int*)(Bs + (size_t)(h2 * 256 + w * 64) * 8), 16, 0, 0);
            __builtin_amdgcn_global_load_lds(
                (const unsigned int*)(WtC + widx),
                (unsigned int*)(Cs + (size_t)(h2 * 256 + w * 64) * 8), 16, 0, 0);
        }
        __syncthreads();
#pragma unroll
        for (int ks = 0; ks < BK; ks += 32) {
            short8 af[4], bf[2], cf[2];
#pragma unroll
            for (int mt = 0; mt < 4; ++mt) {
                int ar = wm * 64 + mt * 16 + l16;
                int acb = ((ks >> 3) + quad) ^ (ar & 7);
                af[mt] = *(const short8*)&As[ar * BK + acb * 8];
            }
#pragma unroll
            for (int nt = 0; nt < 2; ++nt) {
                int br = wn * 32 + nt * 16 + l16;
                int bcb = ((ks >> 3) + quad) ^ (br & 7);
                bf[nt] = *(const short8*)&Bs[br * BK + bcb * 8];
                cf[nt] = *(const short8*)&Cs[br * BK + bcb * 8];
            }
#pragma unroll
            for (int mt = 0; mt < 4; ++mt)
#pragma unroll
                for (int nt = 0; nt < 2; ++nt) {
                    acc1[mt][nt] = __builtin_amdgcn_mfma_f32_16x16x32_bf16(af[mt], bf[nt], acc1[mt][nt], 0, 0, 0);
                    acc2[mt][nt] = __builtin_amdgcn_mfma_f32_16x16x32_bf16(af[mt], cf[nt], acc2[mt][nt], 0, 0, 0);
                }
        }
    }
    // epilogue
#pragma unroll
    for (int mt = 0; mt < 4; ++mt) {
#pragma unroll
        for (int nt = 0; nt < 2; ++nt) {
            int lcol = wn * 32 + nt * 16 + l16;
            int col = n0 + lcol;
            float bu = bupd[col];
            float cv = cvec[col];
            float cmax = 0.f;
#pragma unroll
            for (int r = 0; r < 4; ++r) {
                int row = row0 + wm * 64 + mt * 16 + quad * 4 + r;
                if (row < n) {
                    float dg = (float)deg[row];
                    float v = fmaxf(acc1[mt][nt][r] + dg * (acc2[mt][nt][r] + cv) + bu, 0.f);
                    Out[(size_t)row * NDIM + col] = f2b(v);
                    if (!LAST) Out8[(size_t)row * NDIM + col] = f2fp8(v);
                    if (LAST) cmax = fmaxf(cmax, v);
                }
            }
            if (LAST) atomicMax(&smax[lcol], __float_as_int(cmax));
        }
    }
    if (LAST) {
        __syncthreads();
        if (t < BN) atomicMax(&geInt[n0 + t], smax[t]);
    }
}

// ---------- final ----------
__global__ __launch_bounds__(1024) void out_kernel(const float* __restrict__ ge,
                                                   const float* __restrict__ W_out,
                                                   const float* __restrict__ b_out,
                                                   float* __restrict__ out) {
    __shared__ float red[4][NDIM];
    int t = threadIdx.x & 255;
    int g = threadIdx.x >> 8;
    float acc = 0.f;
#pragma unroll 8
    for (int kk = 0; kk < 64; ++kk) {
        int k = g * 64 + kk;
        acc += ge[k] * W_out[k * NDIM + t];
    }
    red[g][t] = acc;
    __syncthreads();
    if (g == 0)
        out[t] = b_out[t] + red[0][t] + red[1][t] + red[2][t] + red[3][t];
}

// ---------- launch ----------
extern "C" void kernel_launch(void* const* d_in, const int* in_sizes, int n_in,
                              void* d_out, int out_size, void* d_ws, size_t ws_size,
                              hipStream_t stream) {
    const float* nodes      = (const float*)d_in[0];
    const int*   edges      = (const int*)d_in[1];
    const int*   node_types = (const int*)d_in[2];
    const float* type_emb   = (const float*)d_in[3];
    const float* W_proj     = (const float*)d_in[4];
    const float* b_proj     = (const float*)d_in[5];
    const float* W_msg      = (const float*)d_in[6];
    const float* b_msg      = (const float*)d_in[7];
    const float* W_upd      = (const float*)d_in[8];
    const float* b_upd      = (const float*)d_in[9];
    const float* W_out      = (const float*)d_in[10];
    const float* b_out      = (const float*)d_in[11];

    int n = in_sizes[2];
    int E = in_sizes[1] / 2;
    const int* src = edges;
    const int* dst = edges + E;

    size_t off = 0;
    auto alloc = [&](size_t bytes) {
        void* p = (char*)d_ws + off;
        off += (bytes + 255) & ~(size_t)255;
        return p;
    };
    int* deg    = (int*)alloc((size_t)(n + 4096) * 4);
    int* rowptr = (int*)alloc((size_t)(n + 1) * 4);
    int* cursor = (int*)alloc((size_t)n * 4);
    int* bsum   = (int*)alloc((size_t)256 * 4);
    int* col    = (int*)alloc((size_t)(E + 8 * n) * 4);
    unsigned short* WtA = (unsigned short*)alloc((size_t)HOPS * 256 * 256 * 2);
    unsigned short* WtB = (unsigned short*)alloc((size_t)HOPS * 256 * 256 * 2);
    unsigned short* WtC = (unsigned short*)alloc((size_t)HOPS * 256 * 256 * 2);
    unsigned short* Am  = (unsigned short*)alloc((size_t)8 * 256 * 256 * 2);
    unsigned short* BmT = (unsigned short*)alloc((size_t)HOPS * 256 * 256 * 2);
    float* cvec = (float*)alloc((size_t)HOPS * 256 * 4);
    int* geInt  = (int*)alloc((size_t)256 * 4);
    unsigned short* hA  = (unsigned short*)alloc((size_t)(n + 1) * NDIM * 2);
    unsigned short* hB  = (unsigned short*)alloc((size_t)(n + 1) * NDIM * 2);
    unsigned short* Sb  = (unsigned short*)alloc((size_t)n * NDIM * 2);
    unsigned char* h8   = (unsigned char*)alloc((size_t)(n + 1) * NDIM);

    hipMemsetAsync(deg, 0, (size_t)(n + 4096) * 4, stream);
    int hb = (E + 1023) / 1024;    // hist blocks: 4 edges/thread
    int eb = (E + 255) / 256;      // fill blocks
    int pb = (n + 255) / 256;
    int ib = (n + NPB - 1) / NPB;
    int nch = (n + 1023) / 1024;
    prep_mega_kernel<<<hb + 773 + ib, 256, 0, stream>>>(
        dst, deg, E, hb,
        W_msg, W_upd, b_msg, WtB, Am, BmT, cvec, geInt, h8 + (size_t)n * NDIM,
        nodes, node_types, type_emb, W_proj, b_proj, hA, h8, n);
    scan1_mm_kernel<<<nch + 8, 1024, 0, stream>>>(deg, rowptr, bsum, nch, n, Am, BmT, WtA, WtC);
    scan2_kernel<<<nch, 1024, 0, stream>>>(rowptr, cursor, bsum, nch, n);
    fillpad_kernel<<<eb + pb, 256, 0, stream>>>(src, dst, cursor, rowptr, deg, col, E, eb, n);

    unsigned short* h  = hA;
    unsigned short* ho = hB;
    int gx = (n + BM - 1) / BM;
    int ggrid = 8 * ((gx + 7) / 8) * 4;   // XCD-grouped 1D grid (padded, early-exit)
    for (int i = 0; i < HOPS; ++i) {
        agg_kernel<<<(n + 7) / 8, 256, 0, stream>>>(h8, rowptr, col, Sb, n);
        size_t wofs = (size_t)i * 256 * 256;
        if (i == HOPS - 1)
            gemm_hop_kernel<true><<<ggrid, 256, 0, stream>>>(
                Sb, h, deg, WtA + wofs, WtB + wofs, WtC + wofs,
                b_upd + (size_t)i * NDIM, cvec + (size_t)i * NDIM, ho, h8, geInt, n);
        else
            gemm_hop_kernel<false><<<ggrid, 256, 0, stream>>>(
                Sb, h, deg, WtA + wofs, WtB + wofs, WtC + wofs,
                b_upd + (size_t)i * NDIM, cvec + (size_t)i * NDIM, ho, h8, geInt, n);
        unsigned short* tmp = h; h = ho; ho = tmp;
    }
    out_kernel<<<1, 1024, 0, stream>>>((const float*)geInt, W_out, b_out, (float*)d_out);
}